// Round 1
// 918.505 us; speedup vs baseline: 1.1918x; 1.1918x over previous
//
#include <hip/hip_runtime.h>
#include <hip/hip_bf16.h>

// CoaT factorized attention + conv rel-pos-enc. B=8 N=3137 C=768 h=8 c=96 H=W=56.
// Harness tensors are FLOAT32. Compute: pre-convert x/weights to bf16 once, then
// m97-style async-LDS bf16 MFMA GEMMs; intermediates bf16; accumulation fp32.
// R1: assemble (q@kv + crpe) rewritten as MFMA batched GEMM (was scalar ds_read-bound,
//     267us @ MfmaUtil=0). kv carried as bf16 hi+lo pair to keep f32-level precision.

#define BB 8
#define NN 3137
#define HH 8
#define CH 96
#define HW 3136
#define IMG 56
#define MTOK (BB*NN)   // 25096

typedef __bf16 bf16x8 __attribute__((ext_vector_type(8)));
typedef unsigned short u16x8 __attribute__((ext_vector_type(8)));
typedef float  f32x4  __attribute__((ext_vector_type(4)));
typedef float  f32x8  __attribute__((ext_vector_type(8)));

__device__ __forceinline__ void gl_lds16(const void* g, void* l) {
    __builtin_amdgcn_global_load_lds(
        (const __attribute__((address_space(1))) unsigned int*)g,
        (__attribute__((address_space(3))) unsigned int*)l, 16, 0, 0);
}

// ---------------- f32 -> bf16 bulk convert (n8 = element_count/8) ----------------
__global__ __launch_bounds__(256) void cvt_bf16(
    const float* __restrict__ in, unsigned short* __restrict__ out, int n8)
{
    const int i = blockIdx.x * 256 + threadIdx.x;
    if (i < n8) {
        const f32x8 v = ((const f32x8*)in)[i];
        ((u16x8*)out)[i] = (u16x8)__builtin_convertvector(v, bf16x8);
    }
}

// ---------------- GEMM (NT): C[M,Nd] = A[M,K](lda,bf16) @ W[Nd,K]^T(bf16) + bias ----------------
// 128x128 tile, BK=32, 4 waves 64x64 (4x4 of 16x16x32 mfma), global_load_lds width=16.
template<bool OUT_F32>
__global__ __launch_bounds__(256) void gemm_bt(
    const unsigned short* __restrict__ A, int lda,
    const unsigned short* __restrict__ W,
    const float* __restrict__ bias,
    void* __restrict__ Cptr, int ldc,
    int M, int Nd, int K)
{
    __shared__ alignas(16) unsigned short As[128*32];
    __shared__ alignas(16) unsigned short Bs[128*32];
    const int tid  = threadIdx.x;
    const int n0   = blockIdx.x * 128;
    const int m0   = blockIdx.y * 128;
    const int lane = tid & 63;
    const int wave = tid >> 6;
    const int wm   = (wave >> 1) * 64;
    const int wn   = (wave & 1) * 64;
    const int lr   = lane & 15;
    const int quad = lane >> 4;

    // staging: slot s in [0,512): row = s>>2, kcol = (s&3)*8 ; 16B per slot
    const int r0 = tid >> 2, c0 = (tid & 3) * 8;
    const int r1 = r0 + 64;
    int am0 = m0 + r0; if (am0 > M-1) am0 = M-1;
    int am1 = m0 + r1; if (am1 > M-1) am1 = M-1;
    const unsigned short* a0 = A + (size_t)am0*lda + c0;
    const unsigned short* a1 = A + (size_t)am1*lda + c0;
    const unsigned short* w0 = W + (size_t)(n0+r0)*K + c0;
    const unsigned short* w1 = W + (size_t)(n0+r1)*K + c0;
    unsigned short* lA0 = As + tid*8;          // wave-uniform base + lane*16B (m104 rule)
    unsigned short* lA1 = As + (tid+256)*8;
    unsigned short* lB0 = Bs + tid*8;
    unsigned short* lB1 = Bs + (tid+256)*8;

    f32x4 acc[4][4] = {};
    for (int k0 = 0; k0 < K; k0 += 32) {
        __syncthreads();                       // previous iter's LDS reads done
        gl_lds16(a0 + k0, lA0);
        gl_lds16(a1 + k0, lA1);
        gl_lds16(w0 + k0, lB0);
        gl_lds16(w1 + k0, lB1);
        asm volatile("s_waitcnt vmcnt(0)" ::: "memory");
        __syncthreads();
        bf16x8 af[4], bfr[4];
#pragma unroll
        for (int i = 0; i < 4; ++i) {
            af[i]  = *(const bf16x8*)(As + (wm + i*16 + lr)*32 + quad*8);
            bfr[i] = *(const bf16x8*)(Bs + (wn + i*16 + lr)*32 + quad*8);
        }
#pragma unroll
        for (int i = 0; i < 4; ++i)
#pragma unroll
            for (int j = 0; j < 4; ++j)
                acc[i][j] = __builtin_amdgcn_mfma_f32_16x16x32_bf16(af[i], bfr[j], acc[i][j], 0, 0, 0);
    }
    // epilogue: C/D layout col=lane&15, row=quad*4+reg (m89-verified)
#pragma unroll
    for (int j = 0; j < 4; ++j) {
        const int col = n0 + wn + j*16 + lr;
        const float bv = bias[col];
#pragma unroll
        for (int i = 0; i < 4; ++i) {
#pragma unroll
            for (int r = 0; r < 4; ++r) {
                const int row = m0 + wm + i*16 + quad*4 + r;
                if (row < M) {
                    const float v = acc[i][j][r] + bv;
                    if (OUT_F32)
                        ((float*)Cptr)[(size_t)row*ldc + col] = v;
                    else
                        ((__hip_bfloat16*)Cptr)[(size_t)row*ldc + col] = __float2bfloat16(v);
                }
            }
        }
    }
}

// ---------------- softmax stats over tokens: per (b, h*96+c) column ----------------
__global__ __launch_bounds__(256) void ksm_stats(
    const __hip_bfloat16* __restrict__ qkv, float* __restrict__ stats)
{
    const int g  = blockIdx.x * 256 + threadIdx.x;     // 0..6143
    const int b  = g / 768, hc = g % 768;
    const __hip_bfloat16* base = qkv + (size_t)b*NN*2304 + 768 + hc;
    float m[4] = {-1e30f,-1e30f,-1e30f,-1e30f}, s[4] = {0.f,0.f,0.f,0.f};
    int n = 0;
    for (; n + 4 <= NN; n += 4) {
#pragma unroll
        for (int j = 0; j < 4; ++j) {
            const float x = __bfloat162float(base[(size_t)(n+j)*2304]);
            const float mn = fmaxf(m[j], x);
            s[j] = s[j]*__expf(m[j]-mn) + __expf(x-mn);
            m[j] = mn;
        }
    }
    for (; n < NN; ++n) {
        const float x = __bfloat162float(base[(size_t)n*2304]);
        const float mn = fmaxf(m[0], x);
        s[0] = s[0]*__expf(m[0]-mn) + __expf(x-mn);
        m[0] = mn;
    }
    const float M2 = fmaxf(fmaxf(m[0],m[1]), fmaxf(m[2],m[3]));
    const float S  = s[0]*__expf(m[0]-M2) + s[1]*__expf(m[1]-M2)
                   + s[2]*__expf(m[2]-M2) + s[3]*__expf(m[3]-M2);
    stats[2*g]   = M2;
    stats[2*g+1] = S;
}

__global__ __launch_bounds__(256) void zero_f32(float* __restrict__ p, int n)
{
    const int i = blockIdx.x * 256 + threadIdx.x;
    if (i < n) p[i] = 0.f;
}

// ---------------- kv[b,h,c,d] = sum_n softmax(k)[n,c] * v[n,d] ----------------
__global__ __launch_bounds__(256) void kv_accum(
    const __hip_bfloat16* __restrict__ qkv,
    const float* __restrict__ stats,
    float* __restrict__ kvmat)
{
    const int bh = blockIdx.x;              // 0..63
    const int b = bh >> 3, h = bh & 7;
    const int nstart = blockIdx.y * 393;
    int nend = nstart + 393; if (nend > NN) nend = NN;
    __shared__ float smax[96], srs[96];
    __shared__ float krow[4][96], vrow[4][96];
    const int t = threadIdx.x;
    if (t < 96) {
        const int g = b*768 + h*96 + t;
        smax[t] = stats[2*g];
        srs[t]  = 1.0f / stats[2*g+1];
    }
    __syncthreads();
    const int ci = (t >> 4) * 6;            // 16 groups of 6 over c
    const int di = (t & 15) * 6;            // 16 groups of 6 over d
    const __hip_bfloat16* kb = qkv + (size_t)b*NN*2304 + 768 + h*96;
    const __hip_bfloat16* vb = kb + 768;
    float acc[6][6] = {};
    for (int n = nstart; n < nend; n += 4) {
        __syncthreads();
        for (int idx = t; idx < 384; idx += 256) {
            const int r = idx / 96, j = idx % 96;
            const int nn = n + r;
            if (nn < nend) {
                krow[r][j] = __expf(__bfloat162float(kb[(size_t)nn*2304 + j]) - smax[j]) * srs[j];
                vrow[r][j] = __bfloat162float(vb[(size_t)nn*2304 + j]);
            } else { krow[r][j] = 0.f; vrow[r][j] = 0.f; }
        }
        __syncthreads();
#pragma unroll
        for (int r = 0; r < 4; ++r) {
            float kf[6], vf[6];
#pragma unroll
            for (int i = 0; i < 6; ++i) kf[i] = krow[r][ci+i];
#pragma unroll
            for (int j = 0; j < 6; ++j) vf[j] = vrow[r][di+j];
#pragma unroll
            for (int i = 0; i < 6; ++i)
#pragma unroll
                for (int j = 0; j < 6; ++j)
                    acc[i][j] += kf[i] * vf[j];
        }
    }
    float* outp = kvmat + (size_t)bh*9216;
#pragma unroll
    for (int i = 0; i < 6; ++i)
#pragma unroll
        for (int j = 0; j < 6; ++j)
            atomicAdd(&outp[(ci+i)*96 + (di+j)], acc[i][j]);
}

// ---------------- kv f32 [c][d] -> bf16 hi/lo transposed [d][c], row stride 104 ----------------
// Pad 96->104 (52 words): ds_read_b128 across rows lands 2 lanes/4-bank-group (free, m136)
// instead of 8-way at stride 48 words.
__global__ __launch_bounds__(256) void kv_prep(
    const float* __restrict__ kvm, unsigned short* __restrict__ kvb)
{
    const int bh = blockIdx.x;                       // 0..63
    const float* src = kvm + (size_t)bh*9216;
    unsigned short* dst = kvb + (size_t)bh*19968;    // 2 parts x 96 x 104
    for (int i = threadIdx.x; i < 9216; i += 256) {
        const int c = i / 96, d = i % 96;
        const float v = src[i];
        const __hip_bfloat16 hb = __float2bfloat16(v);
        const float lo = v - __bfloat162float(hb);
        const __hip_bfloat16 lb = __float2bfloat16(lo);
        dst[d*104 + c]        = __hip_bfloat16_raw(hb).x;
        dst[9984 + d*104 + c] = __hip_bfloat16_raw(lb).x;
    }
}

// ---------------- att = scale*(q@kv) + pad(q_img*conv_v), MFMA version ----------------
// Per block: 128 tokens x 96 cols for one (b,h). 4 waves x 32 rows.
// A (q) fragments direct from global (rows are K-contiguous, 192B/row exact-fetch);
// B (kv^T hi/lo) staged once to LDS via global_load_lds (linear dest, m104 rule).
__global__ __launch_bounds__(256) void fatt(
    const __hip_bfloat16* __restrict__ qkv,
    const unsigned short* __restrict__ kvb,
    const __hip_bfloat16* __restrict__ cv,
    __hip_bfloat16* __restrict__ att)
{
    __shared__ alignas(16) unsigned short kvs[2*96*104];   // 39.9 KB
    const int tile = blockIdx.x, h = blockIdx.y, b = blockIdx.z;
    const int t = threadIdx.x, lane = t & 63, wave = t >> 6;
    const int lr = lane & 15, quad = lane >> 4;

    // stage kv hi/lo: 2496 x 16B slots, 256 threads -> 9.75 rounds (waves 0-2 do s=9)
    const unsigned short* kg = kvb + (size_t)(b*8 + h)*19968;
#pragma unroll
    for (int s = 0; s < 10; ++s) {
        const int slot = t + s*256;
        if (slot < 2496) gl_lds16(kg + slot*8, kvs + slot*8);
    }

    // A fragments: lane -> row n0+i*16+(lane&15), k = kk*32 + quad*8
    const int n0 = tile*128 + wave*32;
    const unsigned short* qbu = (const unsigned short*)qkv + (size_t)b*NN*2304 + h*96;
    bf16x8 af[2][3];
#pragma unroll
    for (int i = 0; i < 2; ++i) {
        int n = n0 + i*16 + lr; if (n > NN-1) n = NN-1;
#pragma unroll
        for (int kk = 0; kk < 3; ++kk)
            af[i][kk] = *(const bf16x8*)(qbu + (size_t)n*2304 + kk*32 + quad*8);
    }
    asm volatile("s_waitcnt vmcnt(0)" ::: "memory");
    __syncthreads();

    f32x4 acc[2][6] = {};
#pragma unroll
    for (int j = 0; j < 6; ++j) {
#pragma unroll
        for (int kk = 0; kk < 3; ++kk) {
            const bf16x8 bhh = *(const bf16x8*)(kvs + (j*16 + lr)*104 + kk*32 + quad*8);
            const bf16x8 bll = *(const bf16x8*)(kvs + 9984 + (j*16 + lr)*104 + kk*32 + quad*8);
#pragma unroll
            for (int i = 0; i < 2; ++i) {
                acc[i][j] = __builtin_amdgcn_mfma_f32_16x16x32_bf16(af[i][kk], bhh, acc[i][j], 0, 0, 0);
                acc[i][j] = __builtin_amdgcn_mfma_f32_16x16x32_bf16(af[i][kk], bll, acc[i][j], 0, 0, 0);
            }
        }
    }

    // epilogue: row = n0+i*16+quad*4+r, col = j*16+lr (m89 C/D layout); fuse crpe
    const float scale = 0.10206207261596577f;      // 96^-0.5
    const __hip_bfloat16* qb  = (const __hip_bfloat16*)qbu;
    const __hip_bfloat16* cvb = cv + (size_t)(b*8 + h)*HW*96;
    __hip_bfloat16* ab = att + (size_t)b*NN*2304 + h*96;
#pragma unroll
    for (int i = 0; i < 2; ++i) {
#pragma unroll
        for (int j = 0; j < 6; ++j) {
            const int col = j*16 + lr;
#pragma unroll
            for (int r = 0; r < 4; ++r) {
                const int n = n0 + i*16 + quad*4 + r;
                if (n < NN) {
                    float v = scale * acc[i][j][r];
                    if (n > 0) {
                        const float qv = __bfloat162float(qb[(size_t)n*2304 + col]);
                        v += qv * __bfloat162float(cvb[(size_t)(n-1)*96 + col]);
                    }
                    ab[(size_t)n*2304 + col] = __float2bfloat16(v);
                }
            }
        }
    }
}

// ---------------- depthwise conv v2: LDS row-band ring, 32-ch groups ----------------
template<int KS>
__device__ __forceinline__ void dw_band(
    float (*vt)[64][36],
    const __hip_bfloat16* __restrict__ vbase,
    const float* __restrict__ wp, float bv,
    __hip_bfloat16* __restrict__ cvo,
    int y0)
{
    constexpr int P = KS/2;
    const int t = threadIdx.x;
    float wr[KS*KS];
#pragma unroll
    for (int i = 0; i < KS*KS; ++i) wr[i] = wp[i];

    const int spx = t >> 2, sc0 = (t & 3) * 8;     // staging map: 4 threads/pixel
    const int ch = t & 31, xs = t >> 5;            // compute map: 32 ch x 8 x-slots
    const int xbase = xs*7 + 4 - P;

#pragma unroll
    for (int r = -P; r < P; ++r) {
        const int y = y0 + r;
        if (t < 224) {
            f32x8 v8 = {0,0,0,0,0,0,0,0};
            if ((unsigned)y < (unsigned)IMG) {
                const bf16x8 rv = *(const bf16x8*)(vbase + (size_t)(y*IMG + spx)*2304 + sc0);
                v8 = __builtin_convertvector(rv, f32x8);
            }
            float* dst = &vt[(y+8)&7][spx+4][sc0];
            *(f32x4*)dst     = *(f32x4*)&v8;
            *(f32x4*)(dst+4) = *((f32x4*)&v8 + 1);
        }
    }

    for (int yy = y0; yy < y0 + 14; ++yy) {
        {
            const int y = yy + P;
            if (t < 224) {
                f32x8 v8 = {0,0,0,0,0,0,0,0};
                if ((unsigned)y < (unsigned)IMG) {
                    const bf16x8 rv = *(const bf16x8*)(vbase + (size_t)(y*IMG + spx)*2304 + sc0);
                    v8 = __builtin_convertvector(rv, f32x8);
                }
                float* dst = &vt[(y+8)&7][spx+4][sc0];
                *(f32x4*)dst     = *(f32x4*)&v8;
                *(f32x4*)(dst+4) = *((f32x4*)&v8 + 1);
            }
        }
        __syncthreads();
        float acc[7];
#pragma unroll
        for (int j = 0; j < 7; ++j) acc[j] = bv;
        for (int dy = 0; dy < KS; ++dy) {
            const float* rowp = &vt[(yy + dy - P + 8) & 7][0][ch] + xbase*36;
            float win[7 + 2*P];
#pragma unroll
            for (int i = 0; i < 7 + 2*P; ++i) win[i] = rowp[i*36];
#pragma unroll
            for (int dx = 0; dx < KS; ++dx)
#pragma unroll
                for (int j = 0; j < 7; ++j)
                    acc[j] += wr[dy*KS+dx] * win[j+dx];
        }
        const int p0 = yy*IMG + xs*7;
#pragma unroll
        for (int j = 0; j < 7; ++j)
            cvo[(size_t)(p0 + j)*96] = __float2bfloat16(acc[j]);
        __syncthreads();
    }
}

__global__ __launch_bounds__(256) void dwconv2(
    const __hip_bfloat16* __restrict__ qkv,
    const float* __restrict__ w3, const float* __restrict__ b3,
    const float* __restrict__ w5, const float* __restrict__ b5,
    const float* __restrict__ w7, const float* __restrict__ b7,
    __hip_bfloat16* __restrict__ cv)
{
    __shared__ float vt[8][64][36];
    const int band = blockIdx.x, grp = blockIdx.y, b = blockIdx.z;
    const int t = threadIdx.x;
    {
        const int s = t >> 5, i = t & 31;
        const int xi = i >> 2;
        const int xp = (xi < 4) ? xi : 56 + xi;
        const int c0 = (i & 3) * 8;
        const f32x4 z = {0.f, 0.f, 0.f, 0.f};
        *(f32x4*)&vt[s][xp][c0]     = z;
        *(f32x4*)&vt[s][xp][c0+4]   = z;
    }
    const int chbase = grp * 32;
    const int wg = chbase + (t & 31);
    const int h = wg / 96, d = wg % 96;
    const int y0 = band * 14;
    const __hip_bfloat16* vbase = qkv + (size_t)b*NN*2304 + 2304 + 1536 + chbase;
    __hip_bfloat16* cvo = cv + ((size_t)(b*8 + h)*HW)*96 + d;
    if (grp < 6)        dw_band<3>(vt, vbase, w3 + wg*9,        b3[wg],     cvo, y0);
    else if (grp < 15)  dw_band<5>(vt, vbase, w5 + (wg-192)*25, b5[wg-192], cvo, y0);
    else                dw_band<7>(vt, vbase, w7 + (wg-480)*49, b7[wg-480], cvo, y0);
}

extern "C" void kernel_launch(void* const* d_in, const int* in_sizes, int n_in,
                              void* d_out, int out_size, void* d_ws, size_t ws_size,
                              hipStream_t stream)
{
    const float* x      = (const float*)d_in[0];
    const float* qkv_w  = (const float*)d_in[1];
    const float* qkv_b  = (const float*)d_in[2];
    const float* proj_w = (const float*)d_in[3];
    const float* proj_b = (const float*)d_in[4];
    const float* w3 = (const float*)d_in[5];
    const float* b3 = (const float*)d_in[6];
    const float* w5 = (const float*)d_in[7];
    const float* b5 = (const float*)d_in[8];
    const float* w7 = (const float*)d_in[9];
    const float* b7 = (const float*)d_in[10];
    float* out = (float*)d_out;

    // ws layout (~161.3 MB):
    //   qkv bf16 [25096,2304] | shared{ xb bf16 [25096,768] -> cv bf16 [64,3136,96] }
    //   | kvm f32 | stats | qkv_wb bf16 (reused as kvb after step 1) | proj_wb bf16
    char* ws = (char*)d_ws;
    const size_t QKV_B = (size_t)MTOK * 2304 * 2;       // 115,642,368
    const size_t XB_B  = (size_t)MTOK * 768 * 2;        //  38,547,456
    const size_t SH_B  = XB_B;                           //  >= CV_B (38,535,168)
    const size_t KV_B  = (size_t)64 * 9216 * 4;         //   2,359,296
    const size_t ST_B  = 49152;
    const size_t WB_B  = (size_t)2304 * 768 * 2;        //   3,538,944 (>= kvb 2,555,904)
    const size_t PW_B  = (size_t)768 * 768 * 2;        //   1,179,648
    if (ws_size < QKV_B + SH_B + KV_B + ST_B + WB_B + PW_B) return;
    __hip_bfloat16* qkv  = (__hip_bfloat16*)ws;
    unsigned short* xb   = (unsigned short*)(ws + QKV_B);
    __hip_bfloat16* cv   = (__hip_bfloat16*)(ws + QKV_B);           // reuses xb region
    float*          kvm  = (float*)(ws + QKV_B + SH_B);
    float*          stat = (float*)(ws + QKV_B + SH_B + KV_B);
    unsigned short* wb   = (unsigned short*)(ws + QKV_B + SH_B + KV_B + ST_B);
    unsigned short* pwb  = (unsigned short*)(ws + QKV_B + SH_B + KV_B + ST_B + WB_B);

    // 0) convert x and weights to bf16 (one-time; removes per-tile f32 staging)
    cvt_bf16<<<(MTOK*768/8 + 255)/256, 256, 0, stream>>>(x, xb, MTOK*768/8);
    cvt_bf16<<<(2304*768/8 + 255)/256, 256, 0, stream>>>(qkv_w, wb, 2304*768/8);
    cvt_bf16<<<(768*768/8 + 255)/256, 256, 0, stream>>>(proj_w, pwb, 768*768/8);
    // 1) qkv = x @ qkv_w^T + b   -> [25096, 2304] bf16
    gemm_bt<false><<<dim3(18, 197), 256, 0, stream>>>(
        xb, 768, wb, qkv_b, qkv, 2304, MTOK, 2304, 768);
    // 2) zero kv accumulator
    zero_f32<<<2304, 256, 0, stream>>>(kvm, 64*9216);
    // 3) per-column softmax stats of k
    ksm_stats<<<24, 256, 0, stream>>>(qkv, stat);
    // 4) kv = softmax(k)^T @ v
    kv_accum<<<dim3(64, 8), 256, 0, stream>>>(qkv, stat, kvm);
    // 4.5) kv -> bf16 hi/lo transposed (into dead qkv_wb region)
    kv_prep<<<64, 256, 0, stream>>>(kvm, wb);
    // 5) depthwise conv on v image -> cv (overwrites dead xb)
    dwconv2<<<dim3(4, 24, 8), 256, 0, stream>>>(qkv, w3, b3, w5, b5, w7, b7, cv);
    // 6) att = scale * q@kv + crpe  -> dead k-section of qkv buffer (MFMA)
    fatt<<<dim3(25, 8, 8), 256, 0, stream>>>(qkv, wb, cv,
                                             (__hip_bfloat16*)ws + 768);
    // 7) out = att @ proj_w^T + proj_b  -> f32 d_out
    gemm_bt<true><<<dim3(6, 197), 256, 0, stream>>>(
        (const unsigned short*)ws + 768, 2304, pwb, proj_b, out, 768,
        MTOK, 768, 768);
}

// Round 2
// 559.758 us; speedup vs baseline: 1.9556x; 1.6409x over previous
//
#include <hip/hip_runtime.h>
#include <hip/hip_bf16.h>

// CoaT factorized attention + conv rel-pos-enc. B=8 N=3137 C=768 h=8 c=96 H=W=56.
// Harness tensors are FLOAT32. Compute: pre-convert x/weights to bf16 once, then
// m97-style async-LDS bf16 MFMA GEMMs; intermediates bf16; accumulation fp32.
// R1: assemble (q@kv + crpe) rewritten as MFMA batched GEMM. kv carried as bf16
//     hi+lo pair to keep f32-level precision.
// R2: kv_accum de-atomic'd (partials + reduce in kv_prep); ksm_stats eliminated
//     (unnormalized exp + per-column sums, normalize in kv_prep); 16-token vector
//     staging; XCD-bijective block swizzle in gemm_bt (T1/m204).

#define BB 8
#define NN 3137
#define HH 8
#define CH 96
#define HW 3136
#define IMG 56
#define MTOK (BB*NN)   // 25096
#define NCHK 16        // kv K-chunks
#define CTOK 197       // 16*197 = 3152 >= 3137

typedef __bf16 bf16x8 __attribute__((ext_vector_type(8)));
typedef unsigned short u16x8 __attribute__((ext_vector_type(8)));
typedef float  f32x4  __attribute__((ext_vector_type(4)));
typedef float  f32x8  __attribute__((ext_vector_type(8)));

__device__ __forceinline__ void gl_lds16(const void* g, void* l) {
    __builtin_amdgcn_global_load_lds(
        (const __attribute__((address_space(1))) unsigned int*)g,
        (__attribute__((address_space(3))) unsigned int*)l, 16, 0, 0);
}

// ---------------- f32 -> bf16 bulk convert (n8 = element_count/8) ----------------
__global__ __launch_bounds__(256) void cvt_bf16(
    const float* __restrict__ in, unsigned short* __restrict__ out, int n8)
{
    const int i = blockIdx.x * 256 + threadIdx.x;
    if (i < n8) {
        const f32x8 v = ((const f32x8*)in)[i];
        ((u16x8*)out)[i] = (u16x8)__builtin_convertvector(v, bf16x8);
    }
}

// ---------------- GEMM (NT): C[M,Nd] = A[M,K](lda,bf16) @ W[Nd,K]^T(bf16) + bias ----------------
// 128x128 tile, BK=32, 4 waves 64x64 (4x4 of 16x16x32 mfma), global_load_lds width=16.
// XCD-bijective swizzle (m204): consecutive-in-XCD blocks sweep n fastest -> A panel
// reused within an XCD's L2 instead of every XCD streaming all of A.
template<bool OUT_F32>
__global__ __launch_bounds__(256) void gemm_bt(
    const unsigned short* __restrict__ A, int lda,
    const unsigned short* __restrict__ W,
    const float* __restrict__ bias,
    void* __restrict__ Cptr, int ldc,
    int M, int Nd, int K)
{
    __shared__ alignas(16) unsigned short As[128*32];
    __shared__ alignas(16) unsigned short Bs[128*32];
    const int tid  = threadIdx.x;
    // bijective XCD swizzle
    const int nwg = gridDim.x * gridDim.y;
    int orig = blockIdx.y * gridDim.x + blockIdx.x;
    const int q8 = nwg >> 3, r8 = nwg & 7;
    const int xcd = orig & 7, off = orig >> 3;
    const int wgid = (xcd < r8 ? xcd*(q8+1) : r8*(q8+1) + (xcd-r8)*q8) + off;
    const int n0   = (wgid % gridDim.x) * 128;
    const int m0   = (wgid / gridDim.x) * 128;
    const int lane = tid & 63;
    const int wave = tid >> 6;
    const int wm   = (wave >> 1) * 64;
    const int wn   = (wave & 1) * 64;
    const int lr   = lane & 15;
    const int quad = lane >> 4;

    // staging: slot s in [0,512): row = s>>2, kcol = (s&3)*8 ; 16B per slot
    const int r0 = tid >> 2, c0 = (tid & 3) * 8;
    const int r1 = r0 + 64;
    int am0 = m0 + r0; if (am0 > M-1) am0 = M-1;
    int am1 = m0 + r1; if (am1 > M-1) am1 = M-1;
    const unsigned short* a0 = A + (size_t)am0*lda + c0;
    const unsigned short* a1 = A + (size_t)am1*lda + c0;
    const unsigned short* w0 = W + (size_t)(n0+r0)*K + c0;
    const unsigned short* w1 = W + (size_t)(n0+r1)*K + c0;
    unsigned short* lA0 = As + tid*8;          // wave-uniform base + lane*16B (m104 rule)
    unsigned short* lA1 = As + (tid+256)*8;
    unsigned short* lB0 = Bs + tid*8;
    unsigned short* lB1 = Bs + (tid+256)*8;

    f32x4 acc[4][4] = {};
    for (int k0 = 0; k0 < K; k0 += 32) {
        __syncthreads();                       // previous iter's LDS reads done
        gl_lds16(a0 + k0, lA0);
        gl_lds16(a1 + k0, lA1);
        gl_lds16(w0 + k0, lB0);
        gl_lds16(w1 + k0, lB1);
        asm volatile("s_waitcnt vmcnt(0)" ::: "memory");
        __syncthreads();
        bf16x8 af[4], bfr[4];
#pragma unroll
        for (int i = 0; i < 4; ++i) {
            af[i]  = *(const bf16x8*)(As + (wm + i*16 + lr)*32 + quad*8);
            bfr[i] = *(const bf16x8*)(Bs + (wn + i*16 + lr)*32 + quad*8);
        }
#pragma unroll
        for (int i = 0; i < 4; ++i)
#pragma unroll
            for (int j = 0; j < 4; ++j)
                acc[i][j] = __builtin_amdgcn_mfma_f32_16x16x32_bf16(af[i], bfr[j], acc[i][j], 0, 0, 0);
    }
    // epilogue: C/D layout col=lane&15, row=quad*4+reg (m89-verified)
#pragma unroll
    for (int j = 0; j < 4; ++j) {
        const int col = n0 + wn + j*16 + lr;
        const float bv = bias[col];
#pragma unroll
        for (int i = 0; i < 4; ++i) {
#pragma unroll
            for (int r = 0; r < 4; ++r) {
                const int row = m0 + wm + i*16 + quad*4 + r;
                if (row < M) {
                    const float v = acc[i][j][r] + bv;
                    if (OUT_F32)
                        ((float*)Cptr)[(size_t)row*ldc + col] = v;
                    else
                        ((__hip_bfloat16*)Cptr)[(size_t)row*ldc + col] = __float2bfloat16(v);
                }
            }
        }
    }
}

// ---------------- kv partials: kvp[chunk][bh][c][d] = sum_n exp(k[n,c]) * v[n,d] ----------------
// Unnormalized (no max subtraction: k ~ N(0,0.55^2), exp safe in f32). Per-column
// exp-sums accumulated alongside -> spart[chunk][bh][c]. No atomics, no stats pass.
__global__ __launch_bounds__(256) void kv_accum(
    const __hip_bfloat16* __restrict__ qkv,
    float* __restrict__ kvp,      // [NCHK][64][9216]
    float* __restrict__ spart)    // [NCHK][64][96]
{
    const int bh = blockIdx.x;              // 0..63
    const int chunk = blockIdx.y;           // 0..NCHK-1
    const int b = bh >> 3, h = bh & 7;
    const int nstart = chunk * CTOK;
    int nend = nstart + CTOK; if (nend > NN) nend = NN;
    __shared__ float krow[16][96], vrow[16][96];
    __shared__ float sacc[192][8];
    const int t = threadIdx.x;

    // staging map (t<192): token r = t/12, col group c8 = (t%12)*8
    const int sr = t / 12, sc = (t % 12) * 8;
    const __hip_bfloat16* kb = qkv + (size_t)b*NN*2304 + 768 + h*96;
    const __hip_bfloat16* vb = kb + 768;
    float ssum[8] = {};

    const int ci = (t >> 4) * 6;            // 16 groups of 6 over c
    const int di = (t & 15) * 6;            // 16 groups of 6 over d
    float acc[6][6] = {};
    for (int n = nstart; n < nend; n += 16) {
        __syncthreads();
        if (t < 192) {
            const int nn = n + sr;
            if (nn < nend) {
                const bf16x8 kr = *(const bf16x8*)(kb + (size_t)nn*2304 + sc);
                const bf16x8 vr = *(const bf16x8*)(vb + (size_t)nn*2304 + sc);
                const f32x8 kf = __builtin_convertvector(kr, f32x8);
                const f32x8 vf = __builtin_convertvector(vr, f32x8);
                f32x8 ke;
#pragma unroll
                for (int j = 0; j < 8; ++j) { ke[j] = __expf(kf[j]); ssum[j] += ke[j]; }
                *(f32x4*)&krow[sr][sc]   = *(const f32x4*)&ke;
                *(f32x4*)&krow[sr][sc+4] = *((const f32x4*)&ke + 1);
                *(f32x4*)&vrow[sr][sc]   = *(const f32x4*)&vf;
                *(f32x4*)&vrow[sr][sc+4] = *((const f32x4*)&vf + 1);
            } else {
                const f32x4 z = {0.f,0.f,0.f,0.f};
                *(f32x4*)&krow[sr][sc] = z; *(f32x4*)&krow[sr][sc+4] = z;
                *(f32x4*)&vrow[sr][sc] = z; *(f32x4*)&vrow[sr][sc+4] = z;
            }
        }
        __syncthreads();
#pragma unroll 4
        for (int r = 0; r < 16; ++r) {
            float kf[6], vf[6];
#pragma unroll
            for (int i = 0; i < 6; ++i) kf[i] = krow[r][ci+i];
#pragma unroll
            for (int j = 0; j < 6; ++j) vf[j] = vrow[r][di+j];
#pragma unroll
            for (int i = 0; i < 6; ++i)
#pragma unroll
                for (int j = 0; j < 6; ++j)
                    acc[i][j] += kf[i] * vf[j];
        }
    }
    // partial store (plain, coalesced-ish, no atomics)
    float* outp = kvp + (size_t)(chunk*64 + bh)*9216;
#pragma unroll
    for (int i = 0; i < 6; ++i)
#pragma unroll
        for (int j = 0; j < 6; ++j)
            outp[(ci+i)*96 + (di+j)] = acc[i][j];
    // column exp-sum reduce: column c fed by threads t' = c/8 + 12m (elem c&7)
    if (t < 192) {
#pragma unroll
        for (int j = 0; j < 8; ++j) sacc[t][j] = ssum[j];
    }
    __syncthreads();
    if (t < 96) {
        const int g = t >> 3, e = t & 7;
        float S = 0.f;
#pragma unroll
        for (int m = 0; m < 16; ++m) S += sacc[g + 12*m][e];
        spart[(size_t)(chunk*64 + bh)*96 + t] = S;
    }
}

// ---------------- kv reduce+normalize -> bf16 hi/lo transposed [d][c], stride 104 ----------------
__global__ __launch_bounds__(256) void kv_prep(
    const float* __restrict__ kvp, const float* __restrict__ spart,
    unsigned short* __restrict__ kvb)
{
    const int bh = blockIdx.x, y = blockIdx.y;       // y: quarter of c-range
    __shared__ float sinv[24];
    const int t = threadIdx.x;
    const int cbase = y * 24;
    if (t < 24) {
        float S = 0.f;
#pragma unroll
        for (int ch = 0; ch < NCHK; ++ch)
            S += spart[(size_t)(ch*64 + bh)*96 + cbase + t];
        sinv[t] = 1.0f / S;
    }
    __syncthreads();
    unsigned short* dst = kvb + (size_t)bh*19968;    // 2 parts x 96 x 104
    for (int i = t; i < 2304; i += 256) {
        const int ii = y*2304 + i;
        const int c = ii / 96, d = ii % 96;
        float v = 0.f;
#pragma unroll
        for (int ch = 0; ch < NCHK; ++ch)
            v += kvp[(size_t)(ch*64 + bh)*9216 + ii];
        v *= sinv[c - cbase];
        const __hip_bfloat16 hb = __float2bfloat16(v);
        const float lo = v - __bfloat162float(hb);
        const __hip_bfloat16 lb = __float2bfloat16(lo);
        dst[d*104 + c]        = __hip_bfloat16_raw(hb).x;
        dst[9984 + d*104 + c] = __hip_bfloat16_raw(lb).x;
    }
}

// ---------------- att = scale*(q@kv) + pad(q_img*conv_v), MFMA version ----------------
// Per block: 128 tokens x 96 cols for one (b,h). 4 waves x 32 rows.
__global__ __launch_bounds__(256) void fatt(
    const __hip_bfloat16* __restrict__ qkv,
    const unsigned short* __restrict__ kvb,
    const __hip_bfloat16* __restrict__ cv,
    __hip_bfloat16* __restrict__ att)
{
    __shared__ alignas(16) unsigned short kvs[2*96*104];   // 39.9 KB
    const int tile = blockIdx.x, h = blockIdx.y, b = blockIdx.z;
    const int t = threadIdx.x, lane = t & 63, wave = t >> 6;
    const int lr = lane & 15, quad = lane >> 4;

    // stage kv hi/lo: 2496 x 16B slots
    const unsigned short* kg = kvb + (size_t)(b*8 + h)*19968;
#pragma unroll
    for (int s = 0; s < 10; ++s) {
        const int slot = t + s*256;
        if (slot < 2496) gl_lds16(kg + slot*8, kvs + slot*8);
    }

    // A fragments: lane -> row n0+i*16+(lane&15), k = kk*32 + quad*8
    const int n0 = tile*128 + wave*32;
    const unsigned short* qbu = (const unsigned short*)qkv + (size_t)b*NN*2304 + h*96;
    bf16x8 af[2][3];
#pragma unroll
    for (int i = 0; i < 2; ++i) {
        int n = n0 + i*16 + lr; if (n > NN-1) n = NN-1;
#pragma unroll
        for (int kk = 0; kk < 3; ++kk)
            af[i][kk] = *(const bf16x8*)(qbu + (size_t)n*2304 + kk*32 + quad*8);
    }
    asm volatile("s_waitcnt vmcnt(0)" ::: "memory");
    __syncthreads();

    f32x4 acc[2][6] = {};
#pragma unroll
    for (int j = 0; j < 6; ++j) {
#pragma unroll
        for (int kk = 0; kk < 3; ++kk) {
            const bf16x8 bhh = *(const bf16x8*)(kvs + (j*16 + lr)*104 + kk*32 + quad*8);
            const bf16x8 bll = *(const bf16x8*)(kvs + 9984 + (j*16 + lr)*104 + kk*32 + quad*8);
#pragma unroll
            for (int i = 0; i < 2; ++i) {
                acc[i][j] = __builtin_amdgcn_mfma_f32_16x16x32_bf16(af[i][kk], bhh, acc[i][j], 0, 0, 0);
                acc[i][j] = __builtin_amdgcn_mfma_f32_16x16x32_bf16(af[i][kk], bll, acc[i][j], 0, 0, 0);
            }
        }
    }

    // epilogue: row = n0+i*16+quad*4+r, col = j*16+lr (m89 C/D layout); fuse crpe
    const float scale = 0.10206207261596577f;      // 96^-0.5
    const __hip_bfloat16* qb  = (const __hip_bfloat16*)qbu;
    const __hip_bfloat16* cvb = cv + (size_t)(b*8 + h)*HW*96;
    __hip_bfloat16* ab = att + (size_t)b*NN*2304 + h*96;
#pragma unroll
    for (int i = 0; i < 2; ++i) {
#pragma unroll
        for (int j = 0; j < 6; ++j) {
            const int col = j*16 + lr;
#pragma unroll
            for (int r = 0; r < 4; ++r) {
                const int n = n0 + i*16 + quad*4 + r;
                if (n < NN) {
                    float v = scale * acc[i][j][r];
                    if (n > 0) {
                        const float qv = __bfloat162float(qb[(size_t)n*2304 + col]);
                        v += qv * __bfloat162float(cvb[(size_t)(n-1)*96 + col]);
                    }
                    ab[(size_t)n*2304 + col] = __float2bfloat16(v);
                }
            }
        }
    }
}

// ---------------- depthwise conv v2: LDS row-band ring, 32-ch groups ----------------
template<int KS>
__device__ __forceinline__ void dw_band(
    float (*vt)[64][36],
    const __hip_bfloat16* __restrict__ vbase,
    const float* __restrict__ wp, float bv,
    __hip_bfloat16* __restrict__ cvo,
    int y0)
{
    constexpr int P = KS/2;
    const int t = threadIdx.x;
    float wr[KS*KS];
#pragma unroll
    for (int i = 0; i < KS*KS; ++i) wr[i] = wp[i];

    const int spx = t >> 2, sc0 = (t & 3) * 8;     // staging map: 4 threads/pixel
    const int ch = t & 31, xs = t >> 5;            // compute map: 32 ch x 8 x-slots
    const int xbase = xs*7 + 4 - P;

#pragma unroll
    for (int r = -P; r < P; ++r) {
        const int y = y0 + r;
        if (t < 224) {
            f32x8 v8 = {0,0,0,0,0,0,0,0};
            if ((unsigned)y < (unsigned)IMG) {
                const bf16x8 rv = *(const bf16x8*)(vbase + (size_t)(y*IMG + spx)*2304 + sc0);
                v8 = __builtin_convertvector(rv, f32x8);
            }
            float* dst = &vt[(y+8)&7][spx+4][sc0];
            *(f32x4*)dst     = *(f32x4*)&v8;
            *(f32x4*)(dst+4) = *((f32x4*)&v8 + 1);
        }
    }

    for (int yy = y0; yy < y0 + 14; ++yy) {
        {
            const int y = yy + P;
            if (t < 224) {
                f32x8 v8 = {0,0,0,0,0,0,0,0};
                if ((unsigned)y < (unsigned)IMG) {
                    const bf16x8 rv = *(const bf16x8*)(vbase + (size_t)(y*IMG + spx)*2304 + sc0);
                    v8 = __builtin_convertvector(rv, f32x8);
                }
                float* dst = &vt[(y+8)&7][spx+4][sc0];
                *(f32x4*)dst     = *(f32x4*)&v8;
                *(f32x4*)(dst+4) = *((f32x4*)&v8 + 1);
            }
        }
        __syncthreads();
        float acc[7];
#pragma unroll
        for (int j = 0; j < 7; ++j) acc[j] = bv;
        for (int dy = 0; dy < KS; ++dy) {
            const float* rowp = &vt[(yy + dy - P + 8) & 7][0][ch] + xbase*36;
            float win[7 + 2*P];
#pragma unroll
            for (int i = 0; i < 7 + 2*P; ++i) win[i] = rowp[i*36];
#pragma unroll
            for (int dx = 0; dx < KS; ++dx)
#pragma unroll
                for (int j = 0; j < 7; ++j)
                    acc[j] += wr[dy*KS+dx] * win[j+dx];
        }
        const int p0 = yy*IMG + xs*7;
#pragma unroll
        for (int j = 0; j < 7; ++j)
            cvo[(size_t)(p0 + j)*96] = __float2bfloat16(acc[j]);
        __syncthreads();
    }
}

__global__ __launch_bounds__(256) void dwconv2(
    const __hip_bfloat16* __restrict__ qkv,
    const float* __restrict__ w3, const float* __restrict__ b3,
    const float* __restrict__ w5, const float* __restrict__ b5,
    const float* __restrict__ w7, const float* __restrict__ b7,
    __hip_bfloat16* __restrict__ cv)
{
    __shared__ float vt[8][64][36];
    const int band = blockIdx.x, grp = blockIdx.y, b = blockIdx.z;
    const int t = threadIdx.x;
    {
        const int s = t >> 5, i = t & 31;
        const int xi = i >> 2;
        const int xp = (xi < 4) ? xi : 56 + xi;
        const int c0 = (i & 3) * 8;
        const f32x4 z = {0.f, 0.f, 0.f, 0.f};
        *(f32x4*)&vt[s][xp][c0]     = z;
        *(f32x4*)&vt[s][xp][c0+4]   = z;
    }
    const int chbase = grp * 32;
    const int wg = chbase + (t & 31);
    const int h = wg / 96, d = wg % 96;
    const int y0 = band * 14;
    const __hip_bfloat16* vbase = qkv + (size_t)b*NN*2304 + 2304 + 1536 + chbase;
    __hip_bfloat16* cvo = cv + ((size_t)(b*8 + h)*HW)*96 + d;
    if (grp < 6)        dw_band<3>(vt, vbase, w3 + wg*9,        b3[wg],     cvo, y0);
    else if (grp < 15)  dw_band<5>(vt, vbase, w5 + (wg-192)*25, b5[wg-192], cvo, y0);
    else                dw_band<7>(vt, vbase, w7 + (wg-480)*49, b7[wg-480], cvo, y0);
}

extern "C" void kernel_launch(void* const* d_in, const int* in_sizes, int n_in,
                              void* d_out, int out_size, void* d_ws, size_t ws_size,
                              hipStream_t stream)
{
    const float* x      = (const float*)d_in[0];
    const float* qkv_w  = (const float*)d_in[1];
    const float* qkv_b  = (const float*)d_in[2];
    const float* proj_w = (const float*)d_in[3];
    const float* proj_b = (const float*)d_in[4];
    const float* w3 = (const float*)d_in[5];
    const float* b3 = (const float*)d_in[6];
    const float* w5 = (const float*)d_in[7];
    const float* b5 = (const float*)d_in[8];
    const float* w7 = (const float*)d_in[9];
    const float* b7 = (const float*)d_in[10];
    float* out = (float*)d_out;

    // ws layout (~161.3 MB):
    //   qkv bf16 [25096,2304]
    //   | shared{ xb bf16 [25096,768] -> kvp f32 [16][64][9216] + spart -> cv bf16 }
    //   | kvm f32 (unused) | stats (unused) | qkv_wb bf16 (reused as kvb) | proj_wb bf16
    char* ws = (char*)d_ws;
    const size_t QKV_B = (size_t)MTOK * 2304 * 2;       // 115,642,368
    const size_t XB_B  = (size_t)MTOK * 768 * 2;        //  38,547,456
    const size_t SH_B  = XB_B;                           //  >= kvp+spart (38,141,952) and cv
    const size_t KV_B  = (size_t)64 * 9216 * 4;         //   2,359,296
    const size_t ST_B  = 49152;
    const size_t WB_B  = (size_t)2304 * 768 * 2;        //   3,538,944 (>= kvb 2,555,904)
    const size_t PW_B  = (size_t)768 * 768 * 2;         //   1,179,648
    if (ws_size < QKV_B + SH_B + KV_B + ST_B + WB_B + PW_B) return;
    __hip_bfloat16* qkv  = (__hip_bfloat16*)ws;
    unsigned short* xb   = (unsigned short*)(ws + QKV_B);
    float*          kvp  = (float*)(ws + QKV_B);                     // reuses xb region
    float*          spart= (float*)(ws + QKV_B + (size_t)NCHK*64*9216*4);
    __hip_bfloat16* cv   = (__hip_bfloat16*)(ws + QKV_B);            // reuses region after kv_prep
    unsigned short* wb   = (unsigned short*)(ws + QKV_B + SH_B + KV_B + ST_B);
    unsigned short* pwb  = (unsigned short*)(ws + QKV_B + SH_B + KV_B + ST_B + WB_B);

    // 0) convert x and weights to bf16 (one-time)
    cvt_bf16<<<(MTOK*768/8 + 255)/256, 256, 0, stream>>>(x, xb, MTOK*768/8);
    cvt_bf16<<<(2304*768/8 + 255)/256, 256, 0, stream>>>(qkv_w, wb, 2304*768/8);
    cvt_bf16<<<(768*768/8 + 255)/256, 256, 0, stream>>>(proj_w, pwb, 768*768/8);
    // 1) qkv = x @ qkv_w^T + b   -> [25096, 2304] bf16
    gemm_bt<false><<<dim3(18, 197), 256, 0, stream>>>(
        xb, 768, wb, qkv_b, qkv, 2304, MTOK, 2304, 768);
    // 2) kv partials (unnormalized exp) + per-column exp-sums; xb dead -> kvp
    kv_accum<<<dim3(64, NCHK), 256, 0, stream>>>(qkv, kvp, spart);
    // 3) reduce partials, normalize, hi/lo transpose -> kvb (dead qkv_wb region)
    kv_prep<<<dim3(64, 4), 256, 0, stream>>>(kvp, spart, wb);
    // 4) depthwise conv on v image -> cv (overwrites dead kvp)
    dwconv2<<<dim3(4, 24, 8), 256, 0, stream>>>(qkv, w3, b3, w5, b5, w7, b7, cv);
    // 5) att = scale * q@kv + crpe  -> dead k-section of qkv buffer (MFMA)
    fatt<<<dim3(25, 8, 8), 256, 0, stream>>>(qkv, wb, cv,
                                             (__hip_bfloat16*)ws + 768);
    // 6) out = att @ proj_w^T + proj_b  -> f32 d_out
    gemm_bt<true><<<dim3(6, 197), 256, 0, stream>>>(
        (const unsigned short*)ws + 768, 2304, pwb, proj_b, out, 768,
        MTOK, 768, 768);
}

// Round 3
// 514.637 us; speedup vs baseline: 2.1271x; 1.0877x over previous
//
#include <hip/hip_runtime.h>
#include <hip/hip_bf16.h>

// CoaT factorized attention + conv rel-pos-enc. B=8 N=3137 C=768 h=8 c=96 H=W=56.
// Harness tensors are FLOAT32. Compute: pre-convert x/weights to bf16 once, then
// m97-style async-LDS bf16 MFMA GEMMs; intermediates bf16; accumulation fp32.
// R1: assemble (q@kv + crpe) rewritten as MFMA batched GEMM. kv carried as bf16
//     hi+lo pair to keep f32-level precision.
// R2: kv_accum de-atomic'd + ksm_stats folded in; XCD-bijective swizzle in gemm_bt.
// R3: gemm_bt epilogue operand-swapped: mfma(B,A) puts 4 consecutive N-cols per
//     lane -> packed 8B (bf16x4) / 16B (f32x4) C-stores + float4 bias. Was 64
//     scalar 2B stores/thread -> 246MB WRITE for a 115.6MB output (2.13x amp).

#define BB 8
#define NN 3137
#define HH 8
#define CH 96
#define HW 3136
#define IMG 56
#define MTOK (BB*NN)   // 25096
#define NCHK 16        // kv K-chunks
#define CTOK 197       // 16*197 = 3152 >= 3137

typedef __bf16 bf16x8 __attribute__((ext_vector_type(8)));
typedef unsigned short u16x8 __attribute__((ext_vector_type(8)));
typedef unsigned short u16x4 __attribute__((ext_vector_type(4)));
typedef float  f32x4  __attribute__((ext_vector_type(4)));
typedef float  f32x8  __attribute__((ext_vector_type(8)));

__device__ __forceinline__ void gl_lds16(const void* g, void* l) {
    __builtin_amdgcn_global_load_lds(
        (const __attribute__((address_space(1))) unsigned int*)g,
        (__attribute__((address_space(3))) unsigned int*)l, 16, 0, 0);
}

// ---------------- f32 -> bf16 bulk convert (n8 = element_count/8) ----------------
__global__ __launch_bounds__(256) void cvt_bf16(
    const float* __restrict__ in, unsigned short* __restrict__ out, int n8)
{
    const int i = blockIdx.x * 256 + threadIdx.x;
    if (i < n8) {
        const f32x8 v = ((const f32x8*)in)[i];
        ((u16x8*)out)[i] = (u16x8)__builtin_convertvector(v, bf16x8);
    }
}

// ---------------- GEMM (NT): C[M,Nd] = A[M,K](lda,bf16) @ W[Nd,K]^T(bf16) + bias ----------------
// 128x128 tile, BK=32, 4 waves 64x64 (4x4 of 16x16x32 mfma), global_load_lds width=16.
// XCD-bijective swizzle (m204). Operand-swapped MFMA (R3): D = mfma(Bfrag, Afrag)
// -> lane holds M-row = wm+i*16+(lane&15), N-cols = wn+j*16+quad*4+{0..3} contiguous.
template<bool OUT_F32>
__global__ __launch_bounds__(256) void gemm_bt(
    const unsigned short* __restrict__ A, int lda,
    const unsigned short* __restrict__ W,
    const float* __restrict__ bias,
    void* __restrict__ Cptr, int ldc,
    int M, int Nd, int K)
{
    __shared__ alignas(16) unsigned short As[128*32];
    __shared__ alignas(16) unsigned short Bs[128*32];
    const int tid  = threadIdx.x;
    // bijective XCD swizzle
    const int nwg = gridDim.x * gridDim.y;
    int orig = blockIdx.y * gridDim.x + blockIdx.x;
    const int q8 = nwg >> 3, r8 = nwg & 7;
    const int xcd = orig & 7, off = orig >> 3;
    const int wgid = (xcd < r8 ? xcd*(q8+1) : r8*(q8+1) + (xcd-r8)*q8) + off;
    const int n0   = (wgid % gridDim.x) * 128;
    const int m0   = (wgid / gridDim.x) * 128;
    const int lane = tid & 63;
    const int wave = tid >> 6;
    const int wm   = (wave >> 1) * 64;
    const int wn   = (wave & 1) * 64;
    const int lr   = lane & 15;
    const int quad = lane >> 4;

    // staging: slot s in [0,512): row = s>>2, kcol = (s&3)*8 ; 16B per slot
    const int r0 = tid >> 2, c0 = (tid & 3) * 8;
    const int r1 = r0 + 64;
    int am0 = m0 + r0; if (am0 > M-1) am0 = M-1;
    int am1 = m0 + r1; if (am1 > M-1) am1 = M-1;
    const unsigned short* a0 = A + (size_t)am0*lda + c0;
    const unsigned short* a1 = A + (size_t)am1*lda + c0;
    const unsigned short* w0 = W + (size_t)(n0+r0)*K + c0;
    const unsigned short* w1 = W + (size_t)(n0+r1)*K + c0;
    unsigned short* lA0 = As + tid*8;          // wave-uniform base + lane*16B (m104 rule)
    unsigned short* lA1 = As + (tid+256)*8;
    unsigned short* lB0 = Bs + tid*8;
    unsigned short* lB1 = Bs + (tid+256)*8;

    f32x4 acc[4][4] = {};
    for (int k0 = 0; k0 < K; k0 += 32) {
        __syncthreads();                       // previous iter's LDS reads done
        gl_lds16(a0 + k0, lA0);
        gl_lds16(a1 + k0, lA1);
        gl_lds16(w0 + k0, lB0);
        gl_lds16(w1 + k0, lB1);
        asm volatile("s_waitcnt vmcnt(0)" ::: "memory");
        __syncthreads();
        bf16x8 af[4], bfr[4];
#pragma unroll
        for (int i = 0; i < 4; ++i) {
            af[i]  = *(const bf16x8*)(As + (wm + i*16 + lr)*32 + quad*8);
            bfr[i] = *(const bf16x8*)(Bs + (wn + i*16 + lr)*32 + quad*8);
        }
#pragma unroll
        for (int i = 0; i < 4; ++i)
#pragma unroll
            for (int j = 0; j < 4; ++j)
                acc[i][j] = __builtin_amdgcn_mfma_f32_16x16x32_bf16(bfr[j], af[i], acc[i][j], 0, 0, 0);
    }
    // epilogue (swapped layout): row = m0+wm+i*16+lr, cols = n0+wn+j*16+quad*4+{0..3}
#pragma unroll
    for (int i = 0; i < 4; ++i) {
        const int row = m0 + wm + i*16 + lr;
        if (row < M) {
#pragma unroll
            for (int j = 0; j < 4; ++j) {
                const int col = n0 + wn + j*16 + quad*4;
                const f32x4 bv = *(const f32x4*)(bias + col);
                f32x4 v;
#pragma unroll
                for (int r = 0; r < 4; ++r) v[r] = acc[i][j][r] + bv[r];
                if (OUT_F32) {
                    *(f32x4*)&((float*)Cptr)[(size_t)row*ldc + col] = v;
                } else {
                    u16x4 st;
#pragma unroll
                    for (int r = 0; r < 4; ++r)
                        st[r] = __hip_bfloat16_raw(__float2bfloat16(v[r])).x;
                    *(u16x4*)&((__hip_bfloat16*)Cptr)[(size_t)row*ldc + col] = st;
                }
            }
        }
    }
}

// ---------------- kv partials: kvp[chunk][bh][c][d] = sum_n exp(k[n,c]) * v[n,d] ----------------
// Unnormalized (no max subtraction: k ~ N(0,0.55^2), exp safe in f32). Per-column
// exp-sums accumulated alongside -> spart[chunk][bh][c]. No atomics, no stats pass.
__global__ __launch_bounds__(256) void kv_accum(
    const __hip_bfloat16* __restrict__ qkv,
    float* __restrict__ kvp,      // [NCHK][64][9216]
    float* __restrict__ spart)    // [NCHK][64][96]
{
    const int bh = blockIdx.x;              // 0..63
    const int chunk = blockIdx.y;           // 0..NCHK-1
    const int b = bh >> 3, h = bh & 7;
    const int nstart = chunk * CTOK;
    int nend = nstart + CTOK; if (nend > NN) nend = NN;
    __shared__ float krow[16][96], vrow[16][96];
    __shared__ float sacc[192][8];
    const int t = threadIdx.x;

    // staging map (t<192): token r = t/12, col group c8 = (t%12)*8
    const int sr = t / 12, sc = (t % 12) * 8;
    const __hip_bfloat16* kb = qkv + (size_t)b*NN*2304 + 768 + h*96;
    const __hip_bfloat16* vb = kb + 768;
    float ssum[8] = {};

    const int ci = (t >> 4) * 6;            // 16 groups of 6 over c
    const int di = (t & 15) * 6;            // 16 groups of 6 over d
    float acc[6][6] = {};
    for (int n = nstart; n < nend; n += 16) {
        __syncthreads();
        if (t < 192) {
            const int nn = n + sr;
            if (nn < nend) {
                const bf16x8 kr = *(const bf16x8*)(kb + (size_t)nn*2304 + sc);
                const bf16x8 vr = *(const bf16x8*)(vb + (size_t)nn*2304 + sc);
                const f32x8 kf = __builtin_convertvector(kr, f32x8);
                const f32x8 vf = __builtin_convertvector(vr, f32x8);
                f32x8 ke;
#pragma unroll
                for (int j = 0; j < 8; ++j) { ke[j] = __expf(kf[j]); ssum[j] += ke[j]; }
                *(f32x4*)&krow[sr][sc]   = *(const f32x4*)&ke;
                *(f32x4*)&krow[sr][sc+4] = *((const f32x4*)&ke + 1);
                *(f32x4*)&vrow[sr][sc]   = *(const f32x4*)&vf;
                *(f32x4*)&vrow[sr][sc+4] = *((const f32x4*)&vf + 1);
            } else {
                const f32x4 z = {0.f,0.f,0.f,0.f};
                *(f32x4*)&krow[sr][sc] = z; *(f32x4*)&krow[sr][sc+4] = z;
                *(f32x4*)&vrow[sr][sc] = z; *(f32x4*)&vrow[sr][sc+4] = z;
            }
        }
        __syncthreads();
#pragma unroll 4
        for (int r = 0; r < 16; ++r) {
            float kf[6], vf[6];
#pragma unroll
            for (int i = 0; i < 6; ++i) kf[i] = krow[r][ci+i];
#pragma unroll
            for (int j = 0; j < 6; ++j) vf[j] = vrow[r][di+j];
#pragma unroll
            for (int i = 0; i < 6; ++i)
#pragma unroll
                for (int j = 0; j < 6; ++j)
                    acc[i][j] += kf[i] * vf[j];
        }
    }
    // partial store (plain, coalesced-ish, no atomics)
    float* outp = kvp + (size_t)(chunk*64 + bh)*9216;
#pragma unroll
    for (int i = 0; i < 6; ++i)
#pragma unroll
        for (int j = 0; j < 6; ++j)
            outp[(ci+i)*96 + (di+j)] = acc[i][j];
    // column exp-sum reduce: column c fed by threads t' = c/8 + 12m (elem c&7)
    if (t < 192) {
#pragma unroll
        for (int j = 0; j < 8; ++j) sacc[t][j] = ssum[j];
    }
    __syncthreads();
    if (t < 96) {
        const int g = t >> 3, e = t & 7;
        float S = 0.f;
#pragma unroll
        for (int m = 0; m < 16; ++m) S += sacc[g + 12*m][e];
        spart[(size_t)(chunk*64 + bh)*96 + t] = S;
    }
}

// ---------------- kv reduce+normalize -> bf16 hi/lo transposed [d][c], stride 104 ----------------
__global__ __launch_bounds__(256) void kv_prep(
    const float* __restrict__ kvp, const float* __restrict__ spart,
    unsigned short* __restrict__ kvb)
{
    const int bh = blockIdx.x, y = blockIdx.y;       // y: quarter of c-range
    __shared__ float sinv[24];
    const int t = threadIdx.x;
    const int cbase = y * 24;
    if (t < 24) {
        float S = 0.f;
#pragma unroll
        for (int ch = 0; ch < NCHK; ++ch)
            S += spart[(size_t)(ch*64 + bh)*96 + cbase + t];
        sinv[t] = 1.0f / S;
    }
    __syncthreads();
    unsigned short* dst = kvb + (size_t)bh*19968;    // 2 parts x 96 x 104
    for (int i = t; i < 2304; i += 256) {
        const int ii = y*2304 + i;
        const int c = ii / 96, d = ii % 96;
        float v = 0.f;
#pragma unroll
        for (int ch = 0; ch < NCHK; ++ch)
            v += kvp[(size_t)(ch*64 + bh)*9216 + ii];
        v *= sinv[c - cbase];
        const __hip_bfloat16 hb = __float2bfloat16(v);
        const float lo = v - __bfloat162float(hb);
        const __hip_bfloat16 lb = __float2bfloat16(lo);
        dst[d*104 + c]        = __hip_bfloat16_raw(hb).x;
        dst[9984 + d*104 + c] = __hip_bfloat16_raw(lb).x;
    }
}

// ---------------- att = scale*(q@kv) + pad(q_img*conv_v), MFMA version ----------------
// Per block: 128 tokens x 96 cols for one (b,h). 4 waves x 32 rows.
__global__ __launch_bounds__(256) void fatt(
    const __hip_bfloat16* __restrict__ qkv,
    const unsigned short* __restrict__ kvb,
    const __hip_bfloat16* __restrict__ cv,
    __hip_bfloat16* __restrict__ att)
{
    __shared__ alignas(16) unsigned short kvs[2*96*104];   // 39.9 KB
    const int tile = blockIdx.x, h = blockIdx.y, b = blockIdx.z;
    const int t = threadIdx.x, lane = t & 63, wave = t >> 6;
    const int lr = lane & 15, quad = lane >> 4;

    // stage kv hi/lo: 2496 x 16B slots
    const unsigned short* kg = kvb + (size_t)(b*8 + h)*19968;
#pragma unroll
    for (int s = 0; s < 10; ++s) {
        const int slot = t + s*256;
        if (slot < 2496) gl_lds16(kg + slot*8, kvs + slot*8);
    }

    // A fragments: lane -> row n0+i*16+(lane&15), k = kk*32 + quad*8
    const int n0 = tile*128 + wave*32;
    const unsigned short* qbu = (const unsigned short*)qkv + (size_t)b*NN*2304 + h*96;
    bf16x8 af[2][3];
#pragma unroll
    for (int i = 0; i < 2; ++i) {
        int n = n0 + i*16 + lr; if (n > NN-1) n = NN-1;
#pragma unroll
        for (int kk = 0; kk < 3; ++kk)
            af[i][kk] = *(const bf16x8*)(qbu + (size_t)n*2304 + kk*32 + quad*8);
    }
    asm volatile("s_waitcnt vmcnt(0)" ::: "memory");
    __syncthreads();

    f32x4 acc[2][6] = {};
#pragma unroll
    for (int j = 0; j < 6; ++j) {
#pragma unroll
        for (int kk = 0; kk < 3; ++kk) {
            const bf16x8 bhh = *(const bf16x8*)(kvs + (j*16 + lr)*104 + kk*32 + quad*8);
            const bf16x8 bll = *(const bf16x8*)(kvs + 9984 + (j*16 + lr)*104 + kk*32 + quad*8);
#pragma unroll
            for (int i = 0; i < 2; ++i) {
                acc[i][j] = __builtin_amdgcn_mfma_f32_16x16x32_bf16(af[i][kk], bhh, acc[i][j], 0, 0, 0);
                acc[i][j] = __builtin_amdgcn_mfma_f32_16x16x32_bf16(af[i][kk], bll, acc[i][j], 0, 0, 0);
            }
        }
    }

    // epilogue: row = n0+i*16+quad*4+r, col = j*16+lr (m89 C/D layout); fuse crpe
    const float scale = 0.10206207261596577f;      // 96^-0.5
    const __hip_bfloat16* qb  = (const __hip_bfloat16*)qbu;
    const __hip_bfloat16* cvb = cv + (size_t)(b*8 + h)*HW*96;
    __hip_bfloat16* ab = att + (size_t)b*NN*2304 + h*96;
#pragma unroll
    for (int i = 0; i < 2; ++i) {
#pragma unroll
        for (int j = 0; j < 6; ++j) {
            const int col = j*16 + lr;
#pragma unroll
            for (int r = 0; r < 4; ++r) {
                const int n = n0 + i*16 + quad*4 + r;
                if (n < NN) {
                    float v = scale * acc[i][j][r];
                    if (n > 0) {
                        const float qv = __bfloat162float(qb[(size_t)n*2304 + col]);
                        v += qv * __bfloat162float(cvb[(size_t)(n-1)*96 + col]);
                    }
                    ab[(size_t)n*2304 + col] = __float2bfloat16(v);
                }
            }
        }
    }
}

// ---------------- depthwise conv v2: LDS row-band ring, 32-ch groups ----------------
template<int KS>
__device__ __forceinline__ void dw_band(
    float (*vt)[64][36],
    const __hip_bfloat16* __restrict__ vbase,
    const float* __restrict__ wp, float bv,
    __hip_bfloat16* __restrict__ cvo,
    int y0)
{
    constexpr int P = KS/2;
    const int t = threadIdx.x;
    float wr[KS*KS];
#pragma unroll
    for (int i = 0; i < KS*KS; ++i) wr[i] = wp[i];

    const int spx = t >> 2, sc0 = (t & 3) * 8;     // staging map: 4 threads/pixel
    const int ch = t & 31, xs = t >> 5;            // compute map: 32 ch x 8 x-slots
    const int xbase = xs*7 + 4 - P;

#pragma unroll
    for (int r = -P; r < P; ++r) {
        const int y = y0 + r;
        if (t < 224) {
            f32x8 v8 = {0,0,0,0,0,0,0,0};
            if ((unsigned)y < (unsigned)IMG) {
                const bf16x8 rv = *(const bf16x8*)(vbase + (size_t)(y*IMG + spx)*2304 + sc0);
                v8 = __builtin_convertvector(rv, f32x8);
            }
            float* dst = &vt[(y+8)&7][spx+4][sc0];
            *(f32x4*)dst     = *(f32x4*)&v8;
            *(f32x4*)(dst+4) = *((f32x4*)&v8 + 1);
        }
    }

    for (int yy = y0; yy < y0 + 14; ++yy) {
        {
            const int y = yy + P;
            if (t < 224) {
                f32x8 v8 = {0,0,0,0,0,0,0,0};
                if ((unsigned)y < (unsigned)IMG) {
                    const bf16x8 rv = *(const bf16x8*)(vbase + (size_t)(y*IMG + spx)*2304 + sc0);
                    v8 = __builtin_convertvector(rv, f32x8);
                }
                float* dst = &vt[(y+8)&7][spx+4][sc0];
                *(f32x4*)dst     = *(f32x4*)&v8;
                *(f32x4*)(dst+4) = *((f32x4*)&v8 + 1);
            }
        }
        __syncthreads();
        float acc[7];
#pragma unroll
        for (int j = 0; j < 7; ++j) acc[j] = bv;
        for (int dy = 0; dy < KS; ++dy) {
            const float* rowp = &vt[(yy + dy - P + 8) & 7][0][ch] + xbase*36;
            float win[7 + 2*P];
#pragma unroll
            for (int i = 0; i < 7 + 2*P; ++i) win[i] = rowp[i*36];
#pragma unroll
            for (int dx = 0; dx < KS; ++dx)
#pragma unroll
                for (int j = 0; j < 7; ++j)
                    acc[j] += wr[dy*KS+dx] * win[j+dx];
        }
        const int p0 = yy*IMG + xs*7;
#pragma unroll
        for (int j = 0; j < 7; ++j)
            cvo[(size_t)(p0 + j)*96] = __float2bfloat16(acc[j]);
        __syncthreads();
    }
}

__global__ __launch_bounds__(256) void dwconv2(
    const __hip_bfloat16* __restrict__ qkv,
    const float* __restrict__ w3, const float* __restrict__ b3,
    const float* __restrict__ w5, const float* __restrict__ b5,
    const float* __restrict__ w7, const float* __restrict__ b7,
    __hip_bfloat16* __restrict__ cv)
{
    __shared__ float vt[8][64][36];
    const int band = blockIdx.x, grp = blockIdx.y, b = blockIdx.z;
    const int t = threadIdx.x;
    {
        const int s = t >> 5, i = t & 31;
        const int xi = i >> 2;
        const int xp = (xi < 4) ? xi : 56 + xi;
        const int c0 = (i & 3) * 8;
        const f32x4 z = {0.f, 0.f, 0.f, 0.f};
        *(f32x4*)&vt[s][xp][c0]     = z;
        *(f32x4*)&vt[s][xp][c0+4]   = z;
    }
    const int chbase = grp * 32;
    const int wg = chbase + (t & 31);
    const int h = wg / 96, d = wg % 96;
    const int y0 = band * 14;
    const __hip_bfloat16* vbase = qkv + (size_t)b*NN*2304 + 2304 + 1536 + chbase;
    __hip_bfloat16* cvo = cv + ((size_t)(b*8 + h)*HW)*96 + d;
    if (grp < 6)        dw_band<3>(vt, vbase, w3 + wg*9,        b3[wg],     cvo, y0);
    else if (grp < 15)  dw_band<5>(vt, vbase, w5 + (wg-192)*25, b5[wg-192], cvo, y0);
    else                dw_band<7>(vt, vbase, w7 + (wg-480)*49, b7[wg-480], cvo, y0);
}

extern "C" void kernel_launch(void* const* d_in, const int* in_sizes, int n_in,
                              void* d_out, int out_size, void* d_ws, size_t ws_size,
                              hipStream_t stream)
{
    const float* x      = (const float*)d_in[0];
    const float* qkv_w  = (const float*)d_in[1];
    const float* qkv_b  = (const float*)d_in[2];
    const float* proj_w = (const float*)d_in[3];
    const float* proj_b = (const float*)d_in[4];
    const float* w3 = (const float*)d_in[5];
    const float* b3 = (const float*)d_in[6];
    const float* w5 = (const float*)d_in[7];
    const float* b5 = (const float*)d_in[8];
    const float* w7 = (const float*)d_in[9];
    const float* b7 = (const float*)d_in[10];
    float* out = (float*)d_out;

    // ws layout (~161.3 MB):
    //   qkv bf16 [25096,2304]
    //   | shared{ xb bf16 [25096,768] -> kvp f32 [16][64][9216] + spart -> cv bf16 }
    //   | kvm f32 (unused) | stats (unused) | qkv_wb bf16 (reused as kvb) | proj_wb bf16
    char* ws = (char*)d_ws;
    const size_t QKV_B = (size_t)MTOK * 2304 * 2;       // 115,642,368
    const size_t XB_B  = (size_t)MTOK * 768 * 2;        //  38,547,456
    const size_t SH_B  = XB_B;                           //  >= kvp+spart (38,141,952) and cv
    const size_t KV_B  = (size_t)64 * 9216 * 4;         //   2,359,296
    const size_t ST_B  = 49152;
    const size_t WB_B  = (size_t)2304 * 768 * 2;        //   3,538,944 (>= kvb 2,555,904)
    const size_t PW_B  = (size_t)768 * 768 * 2;         //   1,179,648
    if (ws_size < QKV_B + SH_B + KV_B + ST_B + WB_B + PW_B) return;
    __hip_bfloat16* qkv  = (__hip_bfloat16*)ws;
    unsigned short* xb   = (unsigned short*)(ws + QKV_B);
    float*          kvp  = (float*)(ws + QKV_B);                     // reuses xb region
    float*          spart= (float*)(ws + QKV_B + (size_t)NCHK*64*9216*4);
    __hip_bfloat16* cv   = (__hip_bfloat16*)(ws + QKV_B);            // reuses region after kv_prep
    unsigned short* wb   = (unsigned short*)(ws + QKV_B + SH_B + KV_B + ST_B);
    unsigned short* pwb  = (unsigned short*)(ws + QKV_B + SH_B + KV_B + ST_B + WB_B);

    // 0) convert x and weights to bf16 (one-time)
    cvt_bf16<<<(MTOK*768/8 + 255)/256, 256, 0, stream>>>(x, xb, MTOK*768/8);
    cvt_bf16<<<(2304*768/8 + 255)/256, 256, 0, stream>>>(qkv_w, wb, 2304*768/8);
    cvt_bf16<<<(768*768/8 + 255)/256, 256, 0, stream>>>(proj_w, pwb, 768*768/8);
    // 1) qkv = x @ qkv_w^T + b   -> [25096, 2304] bf16
    gemm_bt<false><<<dim3(18, 197), 256, 0, stream>>>(
        xb, 768, wb, qkv_b, qkv, 2304, MTOK, 2304, 768);
    // 2) kv partials (unnormalized exp) + per-column exp-sums; xb dead -> kvp
    kv_accum<<<dim3(64, NCHK), 256, 0, stream>>>(qkv, kvp, spart);
    // 3) reduce partials, normalize, hi/lo transpose -> kvb (dead qkv_wb region)
    kv_prep<<<dim3(64, 4), 256, 0, stream>>>(kvp, spart, wb);
    // 4) depthwise conv on v image -> cv (overwrites dead kvp)
    dwconv2<<<dim3(4, 24, 8), 256, 0, stream>>>(qkv, w3, b3, w5, b5, w7, b7, cv);
    // 5) att = scale * q@kv + crpe  -> dead k-section of qkv buffer (MFMA)
    fatt<<<dim3(25, 8, 8), 256, 0, stream>>>(qkv, wb, cv,
                                             (__hip_bfloat16*)ws + 768);
    // 6) out = att @ proj_w^T + proj_b  -> f32 d_out
    gemm_bt<true><<<dim3(6, 197), 256, 0, stream>>>(
        (const unsigned short*)ws + 768, 2304, pwb, proj_b, out, 768,
        MTOK, 768, 768);
}

// Round 4
// 509.021 us; speedup vs baseline: 2.1506x; 1.0110x over previous
//
#include <hip/hip_runtime.h>
#include <hip/hip_bf16.h>

// CoaT factorized attention + conv rel-pos-enc. B=8 N=3137 C=768 h=8 c=96 H=W=56.
// Harness tensors are FLOAT32. Compute: pre-convert x/weights to bf16 once; bf16
// MFMA GEMMs; intermediates bf16; accumulation fp32.
// R1: assemble -> MFMA fatt (kv as bf16 hi+lo).
// R2: kv_accum de-atomic'd + ksm_stats folded in; XCD swizzle in gemm_bt.
// R3: gemm_bt operand-swapped epilogue -> packed C-stores (write amp 2.13x -> 1x).
// R4: qkv GEMM ported to 256x256 8-phase schedule (T2+T3+T4+T5): BK=64, 8 waves,
//     2-deep dbuf, counted vmcnt(4) at K-tile boundaries (never drained mid-loop),
//     granule-XOR LDS swizzle via pre-swizzled global source + swizzled ds_read,
//     setprio around MFMA clusters. proj stays on the verified 128^2 kernel.

#define BB 8
#define NN 3137
#define HH 8
#define CH 96
#define HW 3136
#define IMG 56
#define MTOK (BB*NN)   // 25096
#define NCHK 16        // kv K-chunks
#define CTOK 197       // 16*197 = 3152 >= 3137

typedef __bf16 bf16x8 __attribute__((ext_vector_type(8)));
typedef unsigned short u16x8 __attribute__((ext_vector_type(8)));
typedef unsigned short u16x4 __attribute__((ext_vector_type(4)));
typedef float  f32x4  __attribute__((ext_vector_type(4)));
typedef float  f32x8  __attribute__((ext_vector_type(8)));

__device__ __forceinline__ void gl_lds16(const void* g, void* l) {
    __builtin_amdgcn_global_load_lds(
        (const __attribute__((address_space(1))) unsigned int*)g,
        (__attribute__((address_space(3))) unsigned int*)l, 16, 0, 0);
}
__device__ __forceinline__ void memfence_bar() {
    asm volatile("" ::: "memory");
    __builtin_amdgcn_s_barrier();
    asm volatile("" ::: "memory");
}

// ---------------- f32 -> bf16 bulk convert (n8 = element_count/8) ----------------
__global__ __launch_bounds__(256) void cvt_bf16(
    const float* __restrict__ in, unsigned short* __restrict__ out, int n8)
{
    const int i = blockIdx.x * 256 + threadIdx.x;
    if (i < n8) {
        const f32x8 v = ((const f32x8*)in)[i];
        ((u16x8*)out)[i] = (u16x8)__builtin_convertvector(v, bf16x8);
    }
}

// ---------------- 256x256 8-phase GEMM (NT): C[M,Nd]=A[M,K]@W[Nd,K]^T + bias, bf16 out ----
// 8 waves (2M x 4N), per-wave 128x64 out. LDS 128KB: [parity][mat][half][128*64] bf16.
// Swizzle: LDS holds granule g16 of a row at slot (g16 ^ (row&7)); staging pre-swizzles
// the global source (within-row permutation -> coalescing unchanged); reads XOR back.
// Stage plan per K-tile t (1 half per phase): ph0 A0(t+1) ph1 A1(t+1) ph2 B0(t+2)
// ph3 B1(t+2); boundary s_waitcnt vmcnt(4) (0 at t=NT-2); 1 barrier/phase.
__global__ __launch_bounds__(512, 2) void gemm256(
    const unsigned short* __restrict__ A,
    const unsigned short* __restrict__ W,
    const float* __restrict__ bias,
    unsigned short* __restrict__ C,
    int lda, int ldw, int ldc, int M, int NT)
{
    __shared__ alignas(16) unsigned short lds[2*2*2*8192];
    const int tid = threadIdx.x;
    // bijective XCD swizzle (m204)
    const int nwg = gridDim.x * gridDim.y;
    const int orig = blockIdx.y * gridDim.x + blockIdx.x;
    const int q8 = nwg >> 3, r8 = nwg & 7;
    const int xcd = orig & 7, off = orig >> 3;
    const int wgid = (xcd < r8 ? xcd*(q8+1) : r8*(q8+1) + (xcd-r8)*q8) + off;
    const int n0 = (wgid % gridDim.x) * 256;
    const int m0 = (wgid / gridDim.x) * 256;

    const int lane = tid & 63, wave = tid >> 6;
    const int lr = lane & 15, quad = lane >> 4;
    const int wm2 = wave >> 2;          // M half (0/1)
    const int wn4 = wave & 3;           // N quarter
    const int bh  = wn4 >> 1;           // B half this wave reads
    const int brow = (wn4 & 1) * 64;    // row base within B half

    // staging slots: s = tid, tid+512 ; row = s>>3, granule kc = s&7 (16B each)
    const int srow0 = tid >> 3, skc0 = tid & 7;
    const int srow1 = (tid + 512) >> 3, skc1 = tid & 7; // +512 keeps kc, row += 64
    const int kce0 = (skc0 ^ (srow0 & 7)) * 8;          // pre-swizzled src elem offset
    const int kce1 = (skc1 ^ (srow1 & 7)) * 8;

    // stage one half-tile: mat 0=A,1=B, half h, K-tile t, into parity p
    auto stage = [&](int p, int mat, int h, int t) {
        unsigned short* dst = lds + (((p*2 + mat)*2 + h) << 13);
        const int kb = t * 64;
        if (mat == 0) {
            int g0 = m0 + h*128 + srow0; if (g0 > M-1) g0 = M-1;
            int g1 = m0 + h*128 + srow1; if (g1 > M-1) g1 = M-1;
            gl_lds16(A + (size_t)g0*lda + kb + kce0, dst + tid*8);
            gl_lds16(A + (size_t)g1*lda + kb + kce1, dst + (tid+512)*8);
        } else {
            const int g0 = n0 + h*128 + srow0;
            const int g1 = n0 + h*128 + srow1;
            gl_lds16(W + (size_t)g0*ldw + kb + kce0, dst + tid*8);
            gl_lds16(W + (size_t)g1*ldw + kb + kce1, dst + (tid+512)*8);
        }
    };
    // swizzled LDS fragment read: rowh in [0,128), c16 in [0,8)
    auto ldsrd = [&](const unsigned short* base, int rowh, int c16) -> bf16x8 {
        return *(const bf16x8*)(base + rowh*64 + ((c16 ^ (rowh & 7)) << 3));
    };

    // prologue: B(0), A(0), B(1) ; need first 8 loads landed -> vmcnt(4)
    stage(0,1,0,0); stage(0,1,1,0);
    stage(0,0,0,0); stage(0,0,1,0);
    stage(1,1,0,1); stage(1,1,1,1);
    asm volatile("s_waitcnt vmcnt(4)" ::: "memory");
    memfence_bar();

    f32x4 acc[8][4] = {};
    bf16x8 bfr[4][2], af[2][2];
    for (int t = 0; t < NT; ++t) {
        const int p = t & 1;
        const unsigned short* Abuf = lds + (((p*2 + 0)*2 + wm2) << 13);
        const unsigned short* Bbuf = lds + (((p*2 + 1)*2 + bh ) << 13);
#pragma unroll
        for (int q = 0; q < 4; ++q) {
            // ds-reads for this phase (B once per K-tile at ph0)
            if (q == 0) {
#pragma unroll
                for (int j = 0; j < 4; ++j)
#pragma unroll
                    for (int ks = 0; ks < 2; ++ks)
                        bfr[j][ks] = ldsrd(Bbuf, brow + j*16 + lr, ks*4 + quad);
            }
#pragma unroll
            for (int ii = 0; ii < 2; ++ii)
#pragma unroll
                for (int ks = 0; ks < 2; ++ks)
                    af[ii][ks] = ldsrd(Abuf, q*32 + ii*16 + lr, ks*4 + quad);
            // stage issue (1 half-tile per phase)
            if (q == 0) { if (t+1 < NT) stage(p^1, 0, 0, t+1); }
            else if (q == 1) { if (t+1 < NT) stage(p^1, 0, 1, t+1); }
            else if (q == 2) { if (t+2 < NT) stage(p, 1, 0, t+2); }
            else             { if (t+2 < NT) stage(p, 1, 1, t+2); }
            // MFMA cluster (swapped operands: lane&15 = M-row, quad*4+r = N-col)
            __builtin_amdgcn_s_setprio(1);
#pragma unroll
            for (int ii = 0; ii < 2; ++ii)
#pragma unroll
                for (int j = 0; j < 4; ++j)
#pragma unroll
                    for (int ks = 0; ks < 2; ++ks)
                        acc[q*2+ii][j] = __builtin_amdgcn_mfma_f32_16x16x32_bf16(
                            bfr[j][ks], af[ii][ks], acc[q*2+ii][j], 0, 0, 0);
            __builtin_amdgcn_s_setprio(0);
            if (q == 3) {
                if (t+2 < NT)      asm volatile("s_waitcnt vmcnt(4)" ::: "memory");
                else if (t+1 < NT) asm volatile("s_waitcnt vmcnt(0)" ::: "memory");
            }
            memfence_bar();
        }
    }

    // epilogue: row = m0+wm2*128+i*16+lr ; cols = n0+wn4*64+j*16+quad*4+{0..3}
#pragma unroll
    for (int i = 0; i < 8; ++i) {
        const int row = m0 + wm2*128 + i*16 + lr;
        if (row < M) {
#pragma unroll
            for (int j = 0; j < 4; ++j) {
                const int col = n0 + wn4*64 + j*16 + quad*4;
                const f32x4 bv = *(const f32x4*)(bias + col);
                u16x4 st;
#pragma unroll
                for (int r = 0; r < 4; ++r)
                    st[r] = __hip_bfloat16_raw(__float2bfloat16(acc[i][j][r] + bv[r])).x;
                *(u16x4*)&C[(size_t)row*ldc + col] = st;
            }
        }
    }
}

// ---------------- GEMM (NT) 128x128 (proj): C=A@W^T+bias ----------------
template<bool OUT_F32>
__global__ __launch_bounds__(256) void gemm_bt(
    const unsigned short* __restrict__ A, int lda,
    const unsigned short* __restrict__ W,
    const float* __restrict__ bias,
    void* __restrict__ Cptr, int ldc,
    int M, int Nd, int K)
{
    __shared__ alignas(16) unsigned short As[128*32];
    __shared__ alignas(16) unsigned short Bs[128*32];
    const int tid  = threadIdx.x;
    const int nwg = gridDim.x * gridDim.y;
    int orig = blockIdx.y * gridDim.x + blockIdx.x;
    const int q8 = nwg >> 3, r8 = nwg & 7;
    const int xcd = orig & 7, off = orig >> 3;
    const int wgid = (xcd < r8 ? xcd*(q8+1) : r8*(q8+1) + (xcd-r8)*q8) + off;
    const int n0   = (wgid % gridDim.x) * 128;
    const int m0   = (wgid / gridDim.x) * 128;
    const int lane = tid & 63;
    const int wave = tid >> 6;
    const int wm   = (wave >> 1) * 64;
    const int wn   = (wave & 1) * 64;
    const int lr   = lane & 15;
    const int quad = lane >> 4;

    const int r0 = tid >> 2, c0 = (tid & 3) * 8;
    const int r1 = r0 + 64;
    int am0 = m0 + r0; if (am0 > M-1) am0 = M-1;
    int am1 = m0 + r1; if (am1 > M-1) am1 = M-1;
    const unsigned short* a0 = A + (size_t)am0*lda + c0;
    const unsigned short* a1 = A + (size_t)am1*lda + c0;
    const unsigned short* w0 = W + (size_t)(n0+r0)*K + c0;
    const unsigned short* w1 = W + (size_t)(n0+r1)*K + c0;
    unsigned short* lA0 = As + tid*8;
    unsigned short* lA1 = As + (tid+256)*8;
    unsigned short* lB0 = Bs + tid*8;
    unsigned short* lB1 = Bs + (tid+256)*8;

    f32x4 acc[4][4] = {};
    for (int k0 = 0; k0 < K; k0 += 32) {
        __syncthreads();
        gl_lds16(a0 + k0, lA0);
        gl_lds16(a1 + k0, lA1);
        gl_lds16(w0 + k0, lB0);
        gl_lds16(w1 + k0, lB1);
        asm volatile("s_waitcnt vmcnt(0)" ::: "memory");
        __syncthreads();
        bf16x8 af[4], bfr[4];
#pragma unroll
        for (int i = 0; i < 4; ++i) {
            af[i]  = *(const bf16x8*)(As + (wm + i*16 + lr)*32 + quad*8);
            bfr[i] = *(const bf16x8*)(Bs + (wn + i*16 + lr)*32 + quad*8);
        }
#pragma unroll
        for (int i = 0; i < 4; ++i)
#pragma unroll
            for (int j = 0; j < 4; ++j)
                acc[i][j] = __builtin_amdgcn_mfma_f32_16x16x32_bf16(bfr[j], af[i], acc[i][j], 0, 0, 0);
    }
#pragma unroll
    for (int i = 0; i < 4; ++i) {
        const int row = m0 + wm + i*16 + lr;
        if (row < M) {
#pragma unroll
            for (int j = 0; j < 4; ++j) {
                const int col = n0 + wn + j*16 + quad*4;
                const f32x4 bv = *(const f32x4*)(bias + col);
                f32x4 v;
#pragma unroll
                for (int r = 0; r < 4; ++r) v[r] = acc[i][j][r] + bv[r];
                if (OUT_F32) {
                    *(f32x4*)&((float*)Cptr)[(size_t)row*ldc + col] = v;
                } else {
                    u16x4 st;
#pragma unroll
                    for (int r = 0; r < 4; ++r)
                        st[r] = __hip_bfloat16_raw(__float2bfloat16(v[r])).x;
                    *(u16x4*)&((__hip_bfloat16*)Cptr)[(size_t)row*ldc + col] = st;
                }
            }
        }
    }
}

// ---------------- kv partials: kvp[chunk][bh][c][d] = sum_n exp(k[n,c]) * v[n,d] ----------------
__global__ __launch_bounds__(256) void kv_accum(
    const __hip_bfloat16* __restrict__ qkv,
    float* __restrict__ kvp,      // [NCHK][64][9216]
    float* __restrict__ spart)    // [NCHK][64][96]
{
    const int bh = blockIdx.x;              // 0..63
    const int chunk = blockIdx.y;           // 0..NCHK-1
    const int b = bh >> 3, h = bh & 7;
    const int nstart = chunk * CTOK;
    int nend = nstart + CTOK; if (nend > NN) nend = NN;
    __shared__ float krow[16][96], vrow[16][96];
    __shared__ float sacc[192][8];
    const int t = threadIdx.x;

    const int sr = t / 12, sc = (t % 12) * 8;
    const __hip_bfloat16* kb = qkv + (size_t)b*NN*2304 + 768 + h*96;
    const __hip_bfloat16* vb = kb + 768;
    float ssum[8] = {};

    const int ci = (t >> 4) * 6;
    const int di = (t & 15) * 6;
    float acc[6][6] = {};
    for (int n = nstart; n < nend; n += 16) {
        __syncthreads();
        if (t < 192) {
            const int nn = n + sr;
            if (nn < nend) {
                const bf16x8 kr = *(const bf16x8*)(kb + (size_t)nn*2304 + sc);
                const bf16x8 vr = *(const bf16x8*)(vb + (size_t)nn*2304 + sc);
                const f32x8 kf = __builtin_convertvector(kr, f32x8);
                const f32x8 vf = __builtin_convertvector(vr, f32x8);
                f32x8 ke;
#pragma unroll
                for (int j = 0; j < 8; ++j) { ke[j] = __expf(kf[j]); ssum[j] += ke[j]; }
                *(f32x4*)&krow[sr][sc]   = *(const f32x4*)&ke;
                *(f32x4*)&krow[sr][sc+4] = *((const f32x4*)&ke + 1);
                *(f32x4*)&vrow[sr][sc]   = *(const f32x4*)&vf;
                *(f32x4*)&vrow[sr][sc+4] = *((const f32x4*)&vf + 1);
            } else {
                const f32x4 z = {0.f,0.f,0.f,0.f};
                *(f32x4*)&krow[sr][sc] = z; *(f32x4*)&krow[sr][sc+4] = z;
                *(f32x4*)&vrow[sr][sc] = z; *(f32x4*)&vrow[sr][sc+4] = z;
            }
        }
        __syncthreads();
#pragma unroll 4
        for (int r = 0; r < 16; ++r) {
            float kf[6], vf[6];
#pragma unroll
            for (int i = 0; i < 6; ++i) kf[i] = krow[r][ci+i];
#pragma unroll
            for (int j = 0; j < 6; ++j) vf[j] = vrow[r][di+j];
#pragma unroll
            for (int i = 0; i < 6; ++i)
#pragma unroll
                for (int j = 0; j < 6; ++j)
                    acc[i][j] += kf[i] * vf[j];
        }
    }
    float* outp = kvp + (size_t)(chunk*64 + bh)*9216;
#pragma unroll
    for (int i = 0; i < 6; ++i)
#pragma unroll
        for (int j = 0; j < 6; ++j)
            outp[(ci+i)*96 + (di+j)] = acc[i][j];
    if (t < 192) {
#pragma unroll
        for (int j = 0; j < 8; ++j) sacc[t][j] = ssum[j];
    }
    __syncthreads();
    if (t < 96) {
        const int g = t >> 3, e = t & 7;
        float S = 0.f;
#pragma unroll
        for (int m = 0; m < 16; ++m) S += sacc[g + 12*m][e];
        spart[(size_t)(chunk*64 + bh)*96 + t] = S;
    }
}

// ---------------- kv reduce+normalize -> bf16 hi/lo transposed [d][c], stride 104 ----------------
__global__ __launch_bounds__(256) void kv_prep(
    const float* __restrict__ kvp, const float* __restrict__ spart,
    unsigned short* __restrict__ kvb)
{
    const int bh = blockIdx.x, y = blockIdx.y;
    __shared__ float sinv[24];
    const int t = threadIdx.x;
    const int cbase = y * 24;
    if (t < 24) {
        float S = 0.f;
#pragma unroll
        for (int ch = 0; ch < NCHK; ++ch)
            S += spart[(size_t)(ch*64 + bh)*96 + cbase + t];
        sinv[t] = 1.0f / S;
    }
    __syncthreads();
    unsigned short* dst = kvb + (size_t)bh*19968;
    for (int i = t; i < 2304; i += 256) {
        const int ii = y*2304 + i;
        const int c = ii / 96, d = ii % 96;
        float v = 0.f;
#pragma unroll
        for (int ch = 0; ch < NCHK; ++ch)
            v += kvp[(size_t)(ch*64 + bh)*9216 + ii];
        v *= sinv[c - cbase];
        const __hip_bfloat16 hb = __float2bfloat16(v);
        const float lo = v - __bfloat162float(hb);
        const __hip_bfloat16 lb = __float2bfloat16(lo);
        dst[d*104 + c]        = __hip_bfloat16_raw(hb).x;
        dst[9984 + d*104 + c] = __hip_bfloat16_raw(lb).x;
    }
}

// ---------------- att = scale*(q@kv) + pad(q_img*conv_v), MFMA version ----------------
__global__ __launch_bounds__(256) void fatt(
    const __hip_bfloat16* __restrict__ qkv,
    const unsigned short* __restrict__ kvb,
    const __hip_bfloat16* __restrict__ cv,
    __hip_bfloat16* __restrict__ att)
{
    __shared__ alignas(16) unsigned short kvs[2*96*104];
    const int tile = blockIdx.x, h = blockIdx.y, b = blockIdx.z;
    const int t = threadIdx.x, lane = t & 63, wave = t >> 6;
    const int lr = lane & 15, quad = lane >> 4;

    const unsigned short* kg = kvb + (size_t)(b*8 + h)*19968;
#pragma unroll
    for (int s = 0; s < 10; ++s) {
        const int slot = t + s*256;
        if (slot < 2496) gl_lds16(kg + slot*8, kvs + slot*8);
    }

    const int n0 = tile*128 + wave*32;
    const unsigned short* qbu = (const unsigned short*)qkv + (size_t)b*NN*2304 + h*96;
    bf16x8 af[2][3];
#pragma unroll
    for (int i = 0; i < 2; ++i) {
        int n = n0 + i*16 + lr; if (n > NN-1) n = NN-1;
#pragma unroll
        for (int kk = 0; kk < 3; ++kk)
            af[i][kk] = *(const bf16x8*)(qbu + (size_t)n*2304 + kk*32 + quad*8);
    }
    asm volatile("s_waitcnt vmcnt(0)" ::: "memory");
    __syncthreads();

    f32x4 acc[2][6] = {};
#pragma unroll
    for (int j = 0; j < 6; ++j) {
#pragma unroll
        for (int kk = 0; kk < 3; ++kk) {
            const bf16x8 bhh = *(const bf16x8*)(kvs + (j*16 + lr)*104 + kk*32 + quad*8);
            const bf16x8 bll = *(const bf16x8*)(kvs + 9984 + (j*16 + lr)*104 + kk*32 + quad*8);
#pragma unroll
            for (int i = 0; i < 2; ++i) {
                acc[i][j] = __builtin_amdgcn_mfma_f32_16x16x32_bf16(af[i][kk], bhh, acc[i][j], 0, 0, 0);
                acc[i][j] = __builtin_amdgcn_mfma_f32_16x16x32_bf16(af[i][kk], bll, acc[i][j], 0, 0, 0);
            }
        }
    }

    const float scale = 0.10206207261596577f;
    const __hip_bfloat16* qb  = (const __hip_bfloat16*)qbu;
    const __hip_bfloat16* cvb = cv + (size_t)(b*8 + h)*HW*96;
    __hip_bfloat16* ab = att + (size_t)b*NN*2304 + h*96;
#pragma unroll
    for (int i = 0; i < 2; ++i) {
#pragma unroll
        for (int j = 0; j < 6; ++j) {
            const int col = j*16 + lr;
#pragma unroll
            for (int r = 0; r < 4; ++r) {
                const int n = n0 + i*16 + quad*4 + r;
                if (n < NN) {
                    float v = scale * acc[i][j][r];
                    if (n > 0) {
                        const float qv = __bfloat162float(qb[(size_t)n*2304 + col]);
                        v += qv * __bfloat162float(cvb[(size_t)(n-1)*96 + col]);
                    }
                    ab[(size_t)n*2304 + col] = __float2bfloat16(v);
                }
            }
        }
    }
}

// ---------------- depthwise conv v2: LDS row-band ring, 32-ch groups ----------------
template<int KS>
__device__ __forceinline__ void dw_band(
    float (*vt)[64][36],
    const __hip_bfloat16* __restrict__ vbase,
    const float* __restrict__ wp, float bv,
    __hip_bfloat16* __restrict__ cvo,
    int y0)
{
    constexpr int P = KS/2;
    const int t = threadIdx.x;
    float wr[KS*KS];
#pragma unroll
    for (int i = 0; i < KS*KS; ++i) wr[i] = wp[i];

    const int spx = t >> 2, sc0 = (t & 3) * 8;
    const int ch = t & 31, xs = t >> 5;
    const int xbase = xs*7 + 4 - P;

#pragma unroll
    for (int r = -P; r < P; ++r) {
        const int y = y0 + r;
        if (t < 224) {
            f32x8 v8 = {0,0,0,0,0,0,0,0};
            if ((unsigned)y < (unsigned)IMG) {
                const bf16x8 rv = *(const bf16x8*)(vbase + (size_t)(y*IMG + spx)*2304 + sc0);
                v8 = __builtin_convertvector(rv, f32x8);
            }
            float* dst = &vt[(y+8)&7][spx+4][sc0];
            *(f32x4*)dst     = *(f32x4*)&v8;
            *(f32x4*)(dst+4) = *((f32x4*)&v8 + 1);
        }
    }

    for (int yy = y0; yy < y0 + 14; ++yy) {
        {
            const int y = yy + P;
            if (t < 224) {
                f32x8 v8 = {0,0,0,0,0,0,0,0};
                if ((unsigned)y < (unsigned)IMG) {
                    const bf16x8 rv = *(const bf16x8*)(vbase + (size_t)(y*IMG + spx)*2304 + sc0);
                    v8 = __builtin_convertvector(rv, f32x8);
                }
                float* dst = &vt[(y+8)&7][spx+4][sc0];
                *(f32x4*)dst     = *(f32x4*)&v8;
                *(f32x4*)(dst+4) = *((f32x4*)&v8 + 1);
            }
        }
        __syncthreads();
        float acc[7];
#pragma unroll
        for (int j = 0; j < 7; ++j) acc[j] = bv;
        for (int dy = 0; dy < KS; ++dy) {
            const float* rowp = &vt[(yy + dy - P + 8) & 7][0][ch] + xbase*36;
            float win[7 + 2*P];
#pragma unroll
            for (int i = 0; i < 7 + 2*P; ++i) win[i] = rowp[i*36];
#pragma unroll
            for (int dx = 0; dx < KS; ++dx)
#pragma unroll
                for (int j = 0; j < 7; ++j)
                    acc[j] += wr[dy*KS+dx] * win[j+dx];
        }
        const int p0 = yy*IMG + xs*7;
#pragma unroll
        for (int j = 0; j < 7; ++j)
            cvo[(size_t)(p0 + j)*96] = __float2bfloat16(acc[j]);
        __syncthreads();
    }
}

__global__ __launch_bounds__(256) void dwconv2(
    const __hip_bfloat16* __restrict__ qkv,
    const float* __restrict__ w3, const float* __restrict__ b3,
    const float* __restrict__ w5, const float* __restrict__ b5,
    const float* __restrict__ w7, const float* __restrict__ b7,
    __hip_bfloat16* __restrict__ cv)
{
    __shared__ float vt[8][64][36];
    const int band = blockIdx.x, grp = blockIdx.y, b = blockIdx.z;
    const int t = threadIdx.x;
    {
        const int s = t >> 5, i = t & 31;
        const int xi = i >> 2;
        const int xp = (xi < 4) ? xi : 56 + xi;
        const int c0 = (i & 3) * 8;
        const f32x4 z = {0.f, 0.f, 0.f, 0.f};
        *(f32x4*)&vt[s][xp][c0]     = z;
        *(f32x4*)&vt[s][xp][c0+4]   = z;
    }
    const int chbase = grp * 32;
    const int wg = chbase + (t & 31);
    const int h = wg / 96, d = wg % 96;
    const int y0 = band * 14;
    const __hip_bfloat16* vbase = qkv + (size_t)b*NN*2304 + 2304 + 1536 + chbase;
    __hip_bfloat16* cvo = cv + ((size_t)(b*8 + h)*HW)*96 + d;
    if (grp < 6)        dw_band<3>(vt, vbase, w3 + wg*9,        b3[wg],     cvo, y0);
    else if (grp < 15)  dw_band<5>(vt, vbase, w5 + (wg-192)*25, b5[wg-192], cvo, y0);
    else                dw_band<7>(vt, vbase, w7 + (wg-480)*49, b7[wg-480], cvo, y0);
}

extern "C" void kernel_launch(void* const* d_in, const int* in_sizes, int n_in,
                              void* d_out, int out_size, void* d_ws, size_t ws_size,
                              hipStream_t stream)
{
    const float* x      = (const float*)d_in[0];
    const float* qkv_w  = (const float*)d_in[1];
    const float* qkv_b  = (const float*)d_in[2];
    const float* proj_w = (const float*)d_in[3];
    const float* proj_b = (const float*)d_in[4];
    const float* w3 = (const float*)d_in[5];
    const float* b3 = (const float*)d_in[6];
    const float* w5 = (const float*)d_in[7];
    const float* b5 = (const float*)d_in[8];
    const float* w7 = (const float*)d_in[9];
    const float* b7 = (const float*)d_in[10];
    float* out = (float*)d_out;

    char* ws = (char*)d_ws;
    const size_t QKV_B = (size_t)MTOK * 2304 * 2;       // 115,642,368
    const size_t XB_B  = (size_t)MTOK * 768 * 2;        //  38,547,456
    const size_t SH_B  = XB_B;
    const size_t KV_B  = (size_t)64 * 9216 * 4;
    const size_t ST_B  = 49152;
    const size_t WB_B  = (size_t)2304 * 768 * 2;
    const size_t PW_B  = (size_t)768 * 768 * 2;
    if (ws_size < QKV_B + SH_B + KV_B + ST_B + WB_B + PW_B) return;
    __hip_bfloat16* qkv  = (__hip_bfloat16*)ws;
    unsigned short* xb   = (unsigned short*)(ws + QKV_B);
    float*          kvp  = (float*)(ws + QKV_B);
    float*          spart= (float*)(ws + QKV_B + (size_t)NCHK*64*9216*4);
    __hip_bfloat16* cv   = (__hip_bfloat16*)(ws + QKV_B);
    unsigned short* wb   = (unsigned short*)(ws + QKV_B + SH_B + KV_B + ST_B);
    unsigned short* pwb  = (unsigned short*)(ws + QKV_B + SH_B + KV_B + ST_B + WB_B);

    // 0) convert x and weights to bf16 (one-time)
    cvt_bf16<<<(MTOK*768/8 + 255)/256, 256, 0, stream>>>(x, xb, MTOK*768/8);
    cvt_bf16<<<(2304*768/8 + 255)/256, 256, 0, stream>>>(qkv_w, wb, 2304*768/8);
    cvt_bf16<<<(768*768/8 + 255)/256, 256, 0, stream>>>(proj_w, pwb, 768*768/8);
    // 1) qkv = x @ qkv_w^T + b  (256^2 8-phase)  -> [25096, 2304] bf16
    gemm256<<<dim3(9, 99), 512, 0, stream>>>(
        xb, wb, qkv_b, (unsigned short*)qkv, 768, 768, 2304, MTOK, 768/64);
    // 2) kv partials (unnormalized exp) + per-column exp-sums; xb dead -> kvp
    kv_accum<<<dim3(64, NCHK), 256, 0, stream>>>(qkv, kvp, spart);
    // 3) reduce partials, normalize, hi/lo transpose -> kvb (dead qkv_wb region)
    kv_prep<<<dim3(64, 4), 256, 0, stream>>>(kvp, spart, wb);
    // 4) depthwise conv on v image -> cv (overwrites dead kvp)
    dwconv2<<<dim3(4, 24, 8), 256, 0, stream>>>(qkv, w3, b3, w5, b5, w7, b7, cv);
    // 5) att = scale * q@kv + crpe  -> dead k-section of qkv buffer (MFMA)
    fatt<<<dim3(25, 8, 8), 256, 0, stream>>>(qkv, wb, cv,
                                             (__hip_bfloat16*)ws + 768);
    // 6) out = att @ proj_w^T + proj_b  -> f32 d_out
    gemm_bt<true><<<dim3(6, 197), 256, 0, stream>>>(
        (const unsigned short*)ws + 768, 2304, pwb, proj_b, out, 768,
        MTOK, 768, 768);
}

// Round 5
// 502.051 us; speedup vs baseline: 2.1804x; 1.0139x over previous
//
#include <hip/hip_runtime.h>
#include <hip/hip_bf16.h>

// CoaT factorized attention + conv rel-pos-enc. B=8 N=3137 C=768 h=8 c=96 H=W=56.
// R1: assemble -> MFMA fatt (kv as bf16 hi+lo).
// R2: kv_accum de-atomic'd + ksm_stats folded in; XCD swizzle.
// R3: operand-swapped epilogue -> packed C-stores.
// R4: qkv GEMM 256x256 8-phase (landed in drain-mode: compiler vmcnt(0) before
//     C++ ds_reads aliasing global_load_lds -> counted vmcnt defeated).
// R5: gemm256 K-loop LDS reads moved to inline-asm ds_read_b128 (opaque to the
//     compiler's waitcnt pass), m201 two-barrier phase, rule-#18 fence
//     (lgkmcnt(0) + sched_barrier(0)) before each MFMA cluster. Only my vmcnt
//     remains in the loop: vmcnt(4) per K-tile boundary, vmcnt(0) only at tail.

#define BB 8
#define NN 3137
#define HH 8
#define CH 96
#define HW 3136
#define IMG 56
#define MTOK (BB*NN)   // 25096
#define NCHK 16        // kv K-chunks
#define CTOK 197       // 16*197 = 3152 >= 3137

typedef __bf16 bf16x8 __attribute__((ext_vector_type(8)));
typedef unsigned short u16x8 __attribute__((ext_vector_type(8)));
typedef unsigned short u16x4 __attribute__((ext_vector_type(4)));
typedef float  f32x4  __attribute__((ext_vector_type(4)));
typedef float  f32x8  __attribute__((ext_vector_type(8)));

__device__ __forceinline__ void gl_lds16(const void* g, void* l) {
    __builtin_amdgcn_global_load_lds(
        (const __attribute__((address_space(1))) unsigned int*)g,
        (__attribute__((address_space(3))) unsigned int*)l, 16, 0, 0);
}
__device__ __forceinline__ unsigned ldsaddr(const void* p) {
    return (unsigned)(size_t)(const __attribute__((address_space(3))) char*)p;
}
__device__ __forceinline__ bf16x8 ds_rd128(unsigned a) {
    bf16x8 r;
    asm volatile("ds_read_b128 %0, %1" : "=v"(r) : "v"(a));
    return r;
}

// ---------------- f32 -> bf16 bulk convert (n8 = element_count/8) ----------------
__global__ __launch_bounds__(256) void cvt_bf16(
    const float* __restrict__ in, unsigned short* __restrict__ out, int n8)
{
    const int i = blockIdx.x * 256 + threadIdx.x;
    if (i < n8) {
        const f32x8 v = ((const f32x8*)in)[i];
        ((u16x8*)out)[i] = (u16x8)__builtin_convertvector(v, bf16x8);
    }
}

// ---------------- 256x256 8-phase GEMM (NT): C[M,Nd]=A[M,K]@W[Nd,K]^T + bias, bf16 out ----
// 8 waves (2M x 4N), per-wave 128x64 out. LDS 128KB: [parity][mat][half][128*64] bf16.
// Granule-XOR swizzle (pre-swizzled global src + XOR'd asm ds_read; XOR index is
// lane-constant: (ks*4+quad)^(lr&7)). Phase = {asm ds_reads | stage 1 half-tile |
// barrier | lgkmcnt(0)+sched_barrier | setprio(1) 16 MFMA setprio(0) | [vmcnt]
// barrier}. vmcnt(4) once per K-tile (A(t+1),B(t+1) landed; B(t+2) stays in flight).
__global__ __launch_bounds__(512, 2) void gemm256(
    const unsigned short* __restrict__ A,
    const unsigned short* __restrict__ W,
    const float* __restrict__ bias,
    unsigned short* __restrict__ C,
    int lda, int ldw, int ldc, int M, int NT)
{
    __shared__ alignas(16) unsigned short lds[2*2*2*8192];
    const int tid = threadIdx.x;
    // bijective XCD swizzle (m204)
    const int nwg = gridDim.x * gridDim.y;
    const int orig = blockIdx.y * gridDim.x + blockIdx.x;
    const int q8 = nwg >> 3, r8 = nwg & 7;
    const int xcd = orig & 7, off = orig >> 3;
    const int wgid = (xcd < r8 ? xcd*(q8+1) : r8*(q8+1) + (xcd-r8)*q8) + off;
    const int n0 = (wgid % gridDim.x) * 256;
    const int m0 = (wgid / gridDim.x) * 256;

    const int lane = tid & 63, wave = tid >> 6;
    const int lr = lane & 15, quad = lane >> 4;
    const int wm2 = wave >> 2;          // M half (0/1)
    const int wn4 = wave & 3;           // N quarter
    const int bh  = wn4 >> 1;           // B half this wave reads
    const int brow = (wn4 & 1) * 64;    // row base within B half

    // staging slots: s = tid, tid+512 ; row = s>>3, granule kc = s&7 (16B each)
    const int srow0 = tid >> 3, skc0 = tid & 7;
    const int srow1 = (tid + 512) >> 3, skc1 = tid & 7;
    const int kce0 = (skc0 ^ (srow0 & 7)) * 8;          // pre-swizzled src elem offset
    const int kce1 = (skc1 ^ (srow1 & 7)) * 8;

    auto stage = [&](int p, int mat, int h, int t) {
        unsigned short* dst = lds + (((p*2 + mat)*2 + h) << 13);
        const int kb = t * 64;
        if (mat == 0) {
            int g0 = m0 + h*128 + srow0; if (g0 > M-1) g0 = M-1;
            int g1 = m0 + h*128 + srow1; if (g1 > M-1) g1 = M-1;
            gl_lds16(A + (size_t)g0*lda + kb + kce0, dst + tid*8);
            gl_lds16(A + (size_t)g1*lda + kb + kce1, dst + (tid+512)*8);
        } else {
            const int g0 = n0 + h*128 + srow0;
            const int g1 = n0 + h*128 + srow1;
            gl_lds16(W + (size_t)g0*ldw + kb + kce0, dst + tid*8);
            gl_lds16(W + (size_t)g1*ldw + kb + kce1, dst + (tid+512)*8);
        }
    };

    // per-lane constant swizzled byte offsets: row stride 128B; granule (c16^(lr&7))*16B
    const unsigned ldsB = ldsaddr(lds);
    const unsigned swz0 = (unsigned)(((0*4 + quad) ^ (lr & 7)) << 4);  // ks=0
    const unsigned swz1 = (unsigned)(((1*4 + quad) ^ (lr & 7)) << 4);  // ks=1

    // prologue: B(0), A(0), B(1) ; wait A(0),B(0) -> vmcnt(4)
    stage(0,1,0,0); stage(0,1,1,0);
    stage(0,0,0,0); stage(0,0,1,0);
    stage(1,1,0,1); stage(1,1,1,1);
    asm volatile("s_waitcnt vmcnt(4)" ::: "memory");
    __builtin_amdgcn_s_barrier();

    f32x4 acc[8][4] = {};
    bf16x8 bfr[4][2], af[2][2];
    for (int t = 0; t < NT; ++t) {
        const int p = t & 1;
        const unsigned Ab = ldsB + ((unsigned)((p*2 + 0)*2 + wm2) << 14) + (unsigned)lr*128;
        const unsigned Bb = ldsB + ((unsigned)((p*2 + 1)*2 + bh ) << 14) + (unsigned)(brow + lr)*128;
#pragma unroll
        for (int q = 0; q < 4; ++q) {
            // --- issue asm ds_reads (opaque to compiler waitcnt pass) ---
            if (q == 0) {
#pragma unroll
                for (int j = 0; j < 4; ++j) {
                    bfr[j][0] = ds_rd128(Bb + j*16*128 + swz0);
                    bfr[j][1] = ds_rd128(Bb + j*16*128 + swz1);
                }
            }
#pragma unroll
            for (int ii = 0; ii < 2; ++ii) {
                const unsigned ra = Ab + (q*32 + ii*16)*128;
                af[ii][0] = ds_rd128(ra + swz0);
                af[ii][1] = ds_rd128(ra + swz1);
            }
            // --- issue stage (1 half-tile per phase) ---
            if (q == 0)      { if (t+1 < NT) stage(p^1, 0, 0, t+1); }
            else if (q == 1) { if (t+1 < NT) stage(p^1, 0, 1, t+1); }
            else if (q == 2) { if (t+2 < NT) stage(p, 1, 0, t+2); }
            else             { if (t+2 < NT) stage(p, 1, 1, t+2); }
            // --- barrier #1, drain LDS reads, pin order (rule #18) ---
            __builtin_amdgcn_s_barrier();
            asm volatile("s_waitcnt lgkmcnt(0)" ::: "memory");
            __builtin_amdgcn_sched_barrier(0);
            // --- MFMA cluster ---
            __builtin_amdgcn_s_setprio(1);
#pragma unroll
            for (int ii = 0; ii < 2; ++ii)
#pragma unroll
                for (int j = 0; j < 4; ++j)
#pragma unroll
                    for (int ks = 0; ks < 2; ++ks)
                        acc[q*2+ii][j] = __builtin_amdgcn_mfma_f32_16x16x32_bf16(
                            bfr[j][ks], af[ii][ks], acc[q*2+ii][j], 0, 0, 0);
            __builtin_amdgcn_s_setprio(0);
            // --- boundary vmcnt (counted; never 0 until tail), barrier #2 ---
            if (q == 3) {
                if (t+2 < NT)      asm volatile("s_waitcnt vmcnt(4)" ::: "memory");
                else if (t+1 < NT) asm volatile("s_waitcnt vmcnt(0)" ::: "memory");
            }
            __builtin_amdgcn_s_barrier();
        }
    }

    // epilogue: row = m0+wm2*128+i*16+lr ; cols = n0+wn4*64+j*16+quad*4+{0..3}
#pragma unroll
    for (int i = 0; i < 8; ++i) {
        const int row = m0 + wm2*128 + i*16 + lr;
        if (row < M) {
#pragma unroll
            for (int j = 0; j < 4; ++j) {
                const int col = n0 + wn4*64 + j*16 + quad*4;
                const f32x4 bv = *(const f32x4*)(bias + col);
                u16x4 st;
#pragma unroll
                for (int r = 0; r < 4; ++r)
                    st[r] = __hip_bfloat16_raw(__float2bfloat16(acc[i][j][r] + bv[r])).x;
                *(u16x4*)&C[(size_t)row*ldc + col] = st;
            }
        }
    }
}

// ---------------- GEMM (NT) 128x128 (proj): C=A@W^T+bias ----------------
template<bool OUT_F32>
__global__ __launch_bounds__(256) void gemm_bt(
    const unsigned short* __restrict__ A, int lda,
    const unsigned short* __restrict__ W,
    const float* __restrict__ bias,
    void* __restrict__ Cptr, int ldc,
    int M, int Nd, int K)
{
    __shared__ alignas(16) unsigned short As[128*32];
    __shared__ alignas(16) unsigned short Bs[128*32];
    const int tid  = threadIdx.x;
    const int nwg = gridDim.x * gridDim.y;
    int orig = blockIdx.y * gridDim.x + blockIdx.x;
    const int q8 = nwg >> 3, r8 = nwg & 7;
    const int xcd = orig & 7, off = orig >> 3;
    const int wgid = (xcd < r8 ? xcd*(q8+1) : r8*(q8+1) + (xcd-r8)*q8) + off;
    const int n0   = (wgid % gridDim.x) * 128;
    const int m0   = (wgid / gridDim.x) * 128;
    const int lane = tid & 63;
    const int wave = tid >> 6;
    const int wm   = (wave >> 1) * 64;
    const int wn   = (wave & 1) * 64;
    const int lr   = lane & 15;
    const int quad = lane >> 4;

    const int r0 = tid >> 2, c0 = (tid & 3) * 8;
    const int r1 = r0 + 64;
    int am0 = m0 + r0; if (am0 > M-1) am0 = M-1;
    int am1 = m0 + r1; if (am1 > M-1) am1 = M-1;
    const unsigned short* a0 = A + (size_t)am0*lda + c0;
    const unsigned short* a1 = A + (size_t)am1*lda + c0;
    const unsigned short* w0 = W + (size_t)(n0+r0)*K + c0;
    const unsigned short* w1 = W + (size_t)(n0+r1)*K + c0;
    unsigned short* lA0 = As + tid*8;
    unsigned short* lA1 = As + (tid+256)*8;
    unsigned short* lB0 = Bs + tid*8;
    unsigned short* lB1 = Bs + (tid+256)*8;

    f32x4 acc[4][4] = {};
    for (int k0 = 0; k0 < K; k0 += 32) {
        __syncthreads();
        gl_lds16(a0 + k0, lA0);
        gl_lds16(a1 + k0, lA1);
        gl_lds16(w0 + k0, lB0);
        gl_lds16(w1 + k0, lB1);
        asm volatile("s_waitcnt vmcnt(0)" ::: "memory");
        __syncthreads();
        bf16x8 af[4], bfr[4];
#pragma unroll
        for (int i = 0; i < 4; ++i) {
            af[i]  = *(const bf16x8*)(As + (wm + i*16 + lr)*32 + quad*8);
            bfr[i] = *(const bf16x8*)(Bs + (wn + i*16 + lr)*32 + quad*8);
        }
#pragma unroll
        for (int i = 0; i < 4; ++i)
#pragma unroll
            for (int j = 0; j < 4; ++j)
                acc[i][j] = __builtin_amdgcn_mfma_f32_16x16x32_bf16(bfr[j], af[i], acc[i][j], 0, 0, 0);
    }
#pragma unroll
    for (int i = 0; i < 4; ++i) {
        const int row = m0 + wm + i*16 + lr;
        if (row < M) {
#pragma unroll
            for (int j = 0; j < 4; ++j) {
                const int col = n0 + wn + j*16 + quad*4;
                const f32x4 bv = *(const f32x4*)(bias + col);
                f32x4 v;
#pragma unroll
                for (int r = 0; r < 4; ++r) v[r] = acc[i][j][r] + bv[r];
                if (OUT_F32) {
                    *(f32x4*)&((float*)Cptr)[(size_t)row*ldc + col] = v;
                } else {
                    u16x4 st;
#pragma unroll
                    for (int r = 0; r < 4; ++r)
                        st[r] = __hip_bfloat16_raw(__float2bfloat16(v[r])).x;
                    *(u16x4*)&((__hip_bfloat16*)Cptr)[(size_t)row*ldc + col] = st;
                }
            }
        }
    }
}

// ---------------- kv partials: kvp[chunk][bh][c][d] = sum_n exp(k[n,c]) * v[n,d] ----------------
__global__ __launch_bounds__(256) void kv_accum(
    const __hip_bfloat16* __restrict__ qkv,
    float* __restrict__ kvp,      // [NCHK][64][9216]
    float* __restrict__ spart)    // [NCHK][64][96]
{
    const int bh = blockIdx.x;              // 0..63
    const int chunk = blockIdx.y;           // 0..NCHK-1
    const int b = bh >> 3, h = bh & 7;
    const int nstart = chunk * CTOK;
    int nend = nstart + CTOK; if (nend > NN) nend = NN;
    __shared__ float krow[16][96], vrow[16][96];
    __shared__ float sacc[192][8];
    const int t = threadIdx.x;

    const int sr = t / 12, sc = (t % 12) * 8;
    const __hip_bfloat16* kb = qkv + (size_t)b*NN*2304 + 768 + h*96;
    const __hip_bfloat16* vb = kb + 768;
    float ssum[8] = {};

    const int ci = (t >> 4) * 6;
    const int di = (t & 15) * 6;
    float acc[6][6] = {};
    for (int n = nstart; n < nend; n += 16) {
        __syncthreads();
        if (t < 192) {
            const int nn = n + sr;
            if (nn < nend) {
                const bf16x8 kr = *(const bf16x8*)(kb + (size_t)nn*2304 + sc);
                const bf16x8 vr = *(const bf16x8*)(vb + (size_t)nn*2304 + sc);
                const f32x8 kf = __builtin_convertvector(kr, f32x8);
                const f32x8 vf = __builtin_convertvector(vr, f32x8);
                f32x8 ke;
#pragma unroll
                for (int j = 0; j < 8; ++j) { ke[j] = __expf(kf[j]); ssum[j] += ke[j]; }
                *(f32x4*)&krow[sr][sc]   = *(const f32x4*)&ke;
                *(f32x4*)&krow[sr][sc+4] = *((const f32x4*)&ke + 1);
                *(f32x4*)&vrow[sr][sc]   = *(const f32x4*)&vf;
                *(f32x4*)&vrow[sr][sc+4] = *((const f32x4*)&vf + 1);
            } else {
                const f32x4 z = {0.f,0.f,0.f,0.f};
                *(f32x4*)&krow[sr][sc] = z; *(f32x4*)&krow[sr][sc+4] = z;
                *(f32x4*)&vrow[sr][sc] = z; *(f32x4*)&vrow[sr][sc+4] = z;
            }
        }
        __syncthreads();
#pragma unroll 4
        for (int r = 0; r < 16; ++r) {
            float kf[6], vf[6];
#pragma unroll
            for (int i = 0; i < 6; ++i) kf[i] = krow[r][ci+i];
#pragma unroll
            for (int j = 0; j < 6; ++j) vf[j] = vrow[r][di+j];
#pragma unroll
            for (int i = 0; i < 6; ++i)
#pragma unroll
                for (int j = 0; j < 6; ++j)
                    acc[i][j] += kf[i] * vf[j];
        }
    }
    float* outp = kvp + (size_t)(chunk*64 + bh)*9216;
#pragma unroll
    for (int i = 0; i < 6; ++i)
#pragma unroll
        for (int j = 0; j < 6; ++j)
            outp[(ci+i)*96 + (di+j)] = acc[i][j];
    if (t < 192) {
#pragma unroll
        for (int j = 0; j < 8; ++j) sacc[t][j] = ssum[j];
    }
    __syncthreads();
    if (t < 96) {
        const int g = t >> 3, e = t & 7;
        float S = 0.f;
#pragma unroll
        for (int m = 0; m < 16; ++m) S += sacc[g + 12*m][e];
        spart[(size_t)(chunk*64 + bh)*96 + t] = S;
    }
}

// ---------------- kv reduce+normalize -> bf16 hi/lo transposed [d][c], stride 104 ----------------
__global__ __launch_bounds__(256) void kv_prep(
    const float* __restrict__ kvp, const float* __restrict__ spart,
    unsigned short* __restrict__ kvb)
{
    const int bh = blockIdx.x, y = blockIdx.y;
    __shared__ float sinv[24];
    const int t = threadIdx.x;
    const int cbase = y * 24;
    if (t < 24) {
        float S = 0.f;
#pragma unroll
        for (int ch = 0; ch < NCHK; ++ch)
            S += spart[(size_t)(ch*64 + bh)*96 + cbase + t];
        sinv[t] = 1.0f / S;
    }
    __syncthreads();
    unsigned short* dst = kvb + (size_t)bh*19968;
    for (int i = t; i < 2304; i += 256) {
        const int ii = y*2304 + i;
        const int c = ii / 96, d = ii % 96;
        float v = 0.f;
#pragma unroll
        for (int ch = 0; ch < NCHK; ++ch)
            v += kvp[(size_t)(ch*64 + bh)*9216 + ii];
        v *= sinv[c - cbase];
        const __hip_bfloat16 hb = __float2bfloat16(v);
        const float lo = v - __bfloat162float(hb);
        const __hip_bfloat16 lb = __float2bfloat16(lo);
        dst[d*104 + c]        = __hip_bfloat16_raw(hb).x;
        dst[9984 + d*104 + c] = __hip_bfloat16_raw(lb).x;
    }
}

// ---------------- att = scale*(q@kv) + pad(q_img*conv_v), MFMA version ----------------
__global__ __launch_bounds__(256) void fatt(
    const __hip_bfloat16* __restrict__ qkv,
    const unsigned short* __restrict__ kvb,
    const __hip_bfloat16* __restrict__ cv,
    __hip_bfloat16* __restrict__ att)
{
    __shared__ alignas(16) unsigned short kvs[2*96*104];
    const int tile = blockIdx.x, h = blockIdx.y, b = blockIdx.z;
    const int t = threadIdx.x, lane = t & 63, wave = t >> 6;
    const int lr = lane & 15, quad = lane >> 4;

    const unsigned short* kg = kvb + (size_t)(b*8 + h)*19968;
#pragma unroll
    for (int s = 0; s < 10; ++s) {
        const int slot = t + s*256;
        if (slot < 2496) gl_lds16(kg + slot*8, kvs + slot*8);
    }

    const int n0 = tile*128 + wave*32;
    const unsigned short* qbu = (const unsigned short*)qkv + (size_t)b*NN*2304 + h*96;
    bf16x8 af[2][3];
#pragma unroll
    for (int i = 0; i < 2; ++i) {
        int n = n0 + i*16 + lr; if (n > NN-1) n = NN-1;
#pragma unroll
        for (int kk = 0; kk < 3; ++kk)
            af[i][kk] = *(const bf16x8*)(qbu + (size_t)n*2304 + kk*32 + quad*8);
    }
    asm volatile("s_waitcnt vmcnt(0)" ::: "memory");
    __syncthreads();

    f32x4 acc[2][6] = {};
#pragma unroll
    for (int j = 0; j < 6; ++j) {
#pragma unroll
        for (int kk = 0; kk < 3; ++kk) {
            const bf16x8 bhh = *(const bf16x8*)(kvs + (j*16 + lr)*104 + kk*32 + quad*8);
            const bf16x8 bll = *(const bf16x8*)(kvs + 9984 + (j*16 + lr)*104 + kk*32 + quad*8);
#pragma unroll
            for (int i = 0; i < 2; ++i) {
                acc[i][j] = __builtin_amdgcn_mfma_f32_16x16x32_bf16(af[i][kk], bhh, acc[i][j], 0, 0, 0);
                acc[i][j] = __builtin_amdgcn_mfma_f32_16x16x32_bf16(af[i][kk], bll, acc[i][j], 0, 0, 0);
            }
        }
    }

    const float scale = 0.10206207261596577f;
    const __hip_bfloat16* qb  = (const __hip_bfloat16*)qbu;
    const __hip_bfloat16* cvb = cv + (size_t)(b*8 + h)*HW*96;
    __hip_bfloat16* ab = att + (size_t)b*NN*2304 + h*96;
#pragma unroll
    for (int i = 0; i < 2; ++i) {
#pragma unroll
        for (int j = 0; j < 6; ++j) {
            const int col = j*16 + lr;
#pragma unroll
            for (int r = 0; r < 4; ++r) {
                const int n = n0 + i*16 + quad*4 + r;
                if (n < NN) {
                    float v = scale * acc[i][j][r];
                    if (n > 0) {
                        const float qv = __bfloat162float(qb[(size_t)n*2304 + col]);
                        v += qv * __bfloat162float(cvb[(size_t)(n-1)*96 + col]);
                    }
                    ab[(size_t)n*2304 + col] = __float2bfloat16(v);
                }
            }
        }
    }
}

// ---------------- depthwise conv v2: LDS row-band ring, 32-ch groups ----------------
template<int KS>
__device__ __forceinline__ void dw_band(
    float (*vt)[64][36],
    const __hip_bfloat16* __restrict__ vbase,
    const float* __restrict__ wp, float bv,
    __hip_bfloat16* __restrict__ cvo,
    int y0)
{
    constexpr int P = KS/2;
    const int t = threadIdx.x;
    float wr[KS*KS];
#pragma unroll
    for (int i = 0; i < KS*KS; ++i) wr[i] = wp[i];

    const int spx = t >> 2, sc0 = (t & 3) * 8;
    const int ch = t & 31, xs = t >> 5;
    const int xbase = xs*7 + 4 - P;

#pragma unroll
    for (int r = -P; r < P; ++r) {
        const int y = y0 + r;
        if (t < 224) {
            f32x8 v8 = {0,0,0,0,0,0,0,0};
            if ((unsigned)y < (unsigned)IMG) {
                const bf16x8 rv = *(const bf16x8*)(vbase + (size_t)(y*IMG + spx)*2304 + sc0);
                v8 = __builtin_convertvector(rv, f32x8);
            }
            float* dst = &vt[(y+8)&7][spx+4][sc0];
            *(f32x4*)dst     = *(f32x4*)&v8;
            *(f32x4*)(dst+4) = *((f32x4*)&v8 + 1);
        }
    }

    for (int yy = y0; yy < y0 + 14; ++yy) {
        {
            const int y = yy + P;
            if (t < 224) {
                f32x8 v8 = {0,0,0,0,0,0,0,0};
                if ((unsigned)y < (unsigned)IMG) {
                    const bf16x8 rv = *(const bf16x8*)(vbase + (size_t)(y*IMG + spx)*2304 + sc0);
                    v8 = __builtin_convertvector(rv, f32x8);
                }
                float* dst = &vt[(y+8)&7][spx+4][sc0];
                *(f32x4*)dst     = *(f32x4*)&v8;
                *(f32x4*)(dst+4) = *((f32x4*)&v8 + 1);
            }
        }
        __syncthreads();
        float acc[7];
#pragma unroll
        for (int j = 0; j < 7; ++j) acc[j] = bv;
        for (int dy = 0; dy < KS; ++dy) {
            const float* rowp = &vt[(yy + dy - P + 8) & 7][0][ch] + xbase*36;
            float win[7 + 2*P];
#pragma unroll
            for (int i = 0; i < 7 + 2*P; ++i) win[i] = rowp[i*36];
#pragma unroll
            for (int dx = 0; dx < KS; ++dx)
#pragma unroll
                for (int j = 0; j < 7; ++j)
                    acc[j] += wr[dy*KS+dx] * win[j+dx];
        }
        const int p0 = yy*IMG + xs*7;
#pragma unroll
        for (int j = 0; j < 7; ++j)
            cvo[(size_t)(p0 + j)*96] = __float2bfloat16(acc[j]);
        __syncthreads();
    }
}

__global__ __launch_bounds__(256) void dwconv2(
    const __hip_bfloat16* __restrict__ qkv,
    const float* __restrict__ w3, const float* __restrict__ b3,
    const float* __restrict__ w5, const float* __restrict__ b5,
    const float* __restrict__ w7, const float* __restrict__ b7,
    __hip_bfloat16* __restrict__ cv)
{
    __shared__ float vt[8][64][36];
    const int band = blockIdx.x, grp = blockIdx.y, b = blockIdx.z;
    const int t = threadIdx.x;
    {
        const int s = t >> 5, i = t & 31;
        const int xi = i >> 2;
        const int xp = (xi < 4) ? xi : 56 + xi;
        const int c0 = (i & 3) * 8;
        const f32x4 z = {0.f, 0.f, 0.f, 0.f};
        *(f32x4*)&vt[s][xp][c0]     = z;
        *(f32x4*)&vt[s][xp][c0+4]   = z;
    }
    const int chbase = grp * 32;
    const int wg = chbase + (t & 31);
    const int h = wg / 96, d = wg % 96;
    const int y0 = band * 14;
    const __hip_bfloat16* vbase = qkv + (size_t)b*NN*2304 + 2304 + 1536 + chbase;
    __hip_bfloat16* cvo = cv + ((size_t)(b*8 + h)*HW)*96 + d;
    if (grp < 6)        dw_band<3>(vt, vbase, w3 + wg*9,        b3[wg],     cvo, y0);
    else if (grp < 15)  dw_band<5>(vt, vbase, w5 + (wg-192)*25, b5[wg-192], cvo, y0);
    else                dw_band<7>(vt, vbase, w7 + (wg-480)*49, b7[wg-480], cvo, y0);
}

extern "C" void kernel_launch(void* const* d_in, const int* in_sizes, int n_in,
                              void* d_out, int out_size, void* d_ws, size_t ws_size,
                              hipStream_t stream)
{
    const float* x      = (const float*)d_in[0];
    const float* qkv_w  = (const float*)d_in[1];
    const float* qkv_b  = (const float*)d_in[2];
    const float* proj_w = (const float*)d_in[3];
    const float* proj_b = (const float*)d_in[4];
    const float* w3 = (const float*)d_in[5];
    const float* b3 = (const float*)d_in[6];
    const float* w5 = (const float*)d_in[7];
    const float* b5 = (const float*)d_in[8];
    const float* w7 = (const float*)d_in[9];
    const float* b7 = (const float*)d_in[10];
    float* out = (float*)d_out;

    char* ws = (char*)d_ws;
    const size_t QKV_B = (size_t)MTOK * 2304 * 2;       // 115,642,368
    const size_t XB_B  = (size_t)MTOK * 768 * 2;        //  38,547,456
    const size_t SH_B  = XB_B;
    const size_t KV_B  = (size_t)64 * 9216 * 4;
    const size_t ST_B  = 49152;
    const size_t WB_B  = (size_t)2304 * 768 * 2;
    const size_t PW_B  = (size_t)768 * 768 * 2;
    if (ws_size < QKV_B + SH_B + KV_B + ST_B + WB_B + PW_B) return;
    __hip_bfloat16* qkv  = (__hip_bfloat16*)ws;
    unsigned short* xb   = (unsigned short*)(ws + QKV_B);
    float*          kvp  = (float*)(ws + QKV_B);
    float*          spart= (float*)(ws + QKV_B + (size_t)NCHK*64*9216*4);
    __hip_bfloat16* cv   = (__hip_bfloat16*)(ws + QKV_B);
    unsigned short* wb   = (unsigned short*)(ws + QKV_B + SH_B + KV_B + ST_B);
    unsigned short* pwb  = (unsigned short*)(ws + QKV_B + SH_B + KV_B + ST_B + WB_B);

    // 0) convert x and weights to bf16 (one-time)
    cvt_bf16<<<(MTOK*768/8 + 255)/256, 256, 0, stream>>>(x, xb, MTOK*768/8);
    cvt_bf16<<<(2304*768/8 + 255)/256, 256, 0, stream>>>(qkv_w, wb, 2304*768/8);
    cvt_bf16<<<(768*768/8 + 255)/256, 256, 0, stream>>>(proj_w, pwb, 768*768/8);
    // 1) qkv = x @ qkv_w^T + b  (256^2 8-phase, asm ds_read)  -> [25096, 2304] bf16
    gemm256<<<dim3(9, 99), 512, 0, stream>>>(
        xb, wb, qkv_b, (unsigned short*)qkv, 768, 768, 2304, MTOK, 768/64);
    // 2) kv partials (unnormalized exp) + per-column exp-sums; xb dead -> kvp
    kv_accum<<<dim3(64, NCHK), 256, 0, stream>>>(qkv, kvp, spart);
    // 3) reduce partials, normalize, hi/lo transpose -> kvb (dead qkv_wb region)
    kv_prep<<<dim3(64, 4), 256, 0, stream>>>(kvp, spart, wb);
    // 4) depthwise conv on v image -> cv (overwrites dead kvp)
    dwconv2<<<dim3(4, 24, 8), 256, 0, stream>>>(qkv, w3, b3, w5, b5, w7, b7, cv);
    // 5) att = scale * q@kv + crpe  -> dead k-section of qkv buffer (MFMA)
    fatt<<<dim3(25, 8, 8), 256, 0, stream>>>(qkv, wb, cv,
                                             (__hip_bfloat16*)ws + 768);
    // 6) out = att @ proj_w^T + proj_b  -> f32 d_out
    gemm_bt<true><<<dim3(6, 197), 256, 0, stream>>>(
        (const unsigned short*)ws + 768, 2304, pwb, proj_b, out, 768,
        MTOK, 768, 768);
}

// Round 6
// 467.703 us; speedup vs baseline: 2.3405x; 1.0734x over previous
//
#include <hip/hip_runtime.h>
#include <hip/hip_bf16.h>

// CoaT factorized attention + conv rel-pos-enc. B=8 N=3137 C=768 h=8 c=96 H=W=56.
// R1: assemble -> MFMA fatt (kv as bf16 hi+lo).
// R2: kv_accum de-atomic'd + ksm_stats folded in; XCD swizzle.
// R3: operand-swapped epilogue -> packed C-stores.
// R4/R5: qkv GEMM 256x256 8-phase w/ asm ds_read + counted vmcnt (plateau ~147us;
//        keeping it -- marginally better than 128^2's 157).
// R6: (a) kv_accum -> kv_mfma: the 1.85G-FMA outer product moved from VALU
//     (>=23.5us floor) to MFMA via LDS-transposed ekT/vT tiles (pad 40, K=32
//     subtiles, 6 waves x 6 frags). exp sums stay f32; only ek rounds to bf16.
//     (b) gemm256 epilogue: C-tile round-trips dead 128KB LDS in two halves ->
//     1KB fully-coalesced stores (was 64-line scatter per store instr).

#define BB 8
#define NN 3137
#define HH 8
#define CH 96
#define HW 3136
#define IMG 56
#define MTOK (BB*NN)   // 25096
#define NCHK 13        // kv K-chunks
#define CTOK 256       // 8 subtiles of 32 tokens

typedef __bf16 bf16x8 __attribute__((ext_vector_type(8)));
typedef unsigned short u16x8 __attribute__((ext_vector_type(8)));
typedef unsigned short u16x4 __attribute__((ext_vector_type(4)));
typedef float  f32x4  __attribute__((ext_vector_type(4)));
typedef float  f32x8  __attribute__((ext_vector_type(8)));

__device__ __forceinline__ void gl_lds16(const void* g, void* l) {
    __builtin_amdgcn_global_load_lds(
        (const __attribute__((address_space(1))) unsigned int*)g,
        (__attribute__((address_space(3))) unsigned int*)l, 16, 0, 0);
}
__device__ __forceinline__ unsigned ldsaddr(const void* p) {
    return (unsigned)(size_t)(const __attribute__((address_space(3))) char*)p;
}
__device__ __forceinline__ bf16x8 ds_rd128(unsigned a) {
    bf16x8 r;
    asm volatile("ds_read_b128 %0, %1" : "=v"(r) : "v"(a));
    return r;
}
__device__ __forceinline__ unsigned short bf16r(float x) {
    return __hip_bfloat16_raw(__float2bfloat16(x)).x;
}

// ---------------- f32 -> bf16 bulk convert (n8 = element_count/8) ----------------
__global__ __launch_bounds__(256) void cvt_bf16(
    const float* __restrict__ in, unsigned short* __restrict__ out, int n8)
{
    const int i = blockIdx.x * 256 + threadIdx.x;
    if (i < n8) {
        const f32x8 v = ((const f32x8*)in)[i];
        ((u16x8*)out)[i] = (u16x8)__builtin_convertvector(v, bf16x8);
    }
}

// ---------------- 256x256 8-phase GEMM (NT): C[M,Nd]=A[M,K]@W[Nd,K]^T + bias, bf16 out ----
__global__ __launch_bounds__(512, 2) void gemm256(
    const unsigned short* __restrict__ A,
    const unsigned short* __restrict__ W,
    const float* __restrict__ bias,
    unsigned short* __restrict__ C,
    int lda, int ldw, int ldc, int M, int NT)
{
    __shared__ alignas(16) unsigned short lds[2*2*2*8192];
    const int tid = threadIdx.x;
    // bijective XCD swizzle (m204)
    const int nwg = gridDim.x * gridDim.y;
    const int orig = blockIdx.y * gridDim.x + blockIdx.x;
    const int q8 = nwg >> 3, r8 = nwg & 7;
    const int xcd = orig & 7, off = orig >> 3;
    const int wgid = (xcd < r8 ? xcd*(q8+1) : r8*(q8+1) + (xcd-r8)*q8) + off;
    const int n0 = (wgid % gridDim.x) * 256;
    const int m0 = (wgid / gridDim.x) * 256;

    const int lane = tid & 63, wave = tid >> 6;
    const int lr = lane & 15, quad = lane >> 4;
    const int wm2 = wave >> 2;          // M half (0/1)
    const int wn4 = wave & 3;           // N quarter
    const int bh  = wn4 >> 1;           // B half this wave reads
    const int brow = (wn4 & 1) * 64;    // row base within B half

    const int srow0 = tid >> 3, skc0 = tid & 7;
    const int srow1 = (tid + 512) >> 3, skc1 = tid & 7;
    const int kce0 = (skc0 ^ (srow0 & 7)) * 8;
    const int kce1 = (skc1 ^ (srow1 & 7)) * 8;

    auto stage = [&](int p, int mat, int h, int t) {
        unsigned short* dst = lds + (((p*2 + mat)*2 + h) << 13);
        const int kb = t * 64;
        if (mat == 0) {
            int g0 = m0 + h*128 + srow0; if (g0 > M-1) g0 = M-1;
            int g1 = m0 + h*128 + srow1; if (g1 > M-1) g1 = M-1;
            gl_lds16(A + (size_t)g0*lda + kb + kce0, dst + tid*8);
            gl_lds16(A + (size_t)g1*lda + kb + kce1, dst + (tid+512)*8);
        } else {
            const int g0 = n0 + h*128 + srow0;
            const int g1 = n0 + h*128 + srow1;
            gl_lds16(W + (size_t)g0*ldw + kb + kce0, dst + tid*8);
            gl_lds16(W + (size_t)g1*ldw + kb + kce1, dst + (tid+512)*8);
        }
    };

    const unsigned ldsB = ldsaddr(lds);
    const unsigned swz0 = (unsigned)(((0*4 + quad) ^ (lr & 7)) << 4);
    const unsigned swz1 = (unsigned)(((1*4 + quad) ^ (lr & 7)) << 4);

    // prologue
    stage(0,1,0,0); stage(0,1,1,0);
    stage(0,0,0,0); stage(0,0,1,0);
    stage(1,1,0,1); stage(1,1,1,1);
    asm volatile("s_waitcnt vmcnt(4)" ::: "memory");
    __builtin_amdgcn_s_barrier();

    f32x4 acc[8][4] = {};
    bf16x8 bfr[4][2], af[2][2];
    for (int t = 0; t < NT; ++t) {
        const int p = t & 1;
        const unsigned Ab = ldsB + ((unsigned)((p*2 + 0)*2 + wm2) << 14) + (unsigned)lr*128;
        const unsigned Bb = ldsB + ((unsigned)((p*2 + 1)*2 + bh ) << 14) + (unsigned)(brow + lr)*128;
#pragma unroll
        for (int q = 0; q < 4; ++q) {
            if (q == 0) {
#pragma unroll
                for (int j = 0; j < 4; ++j) {
                    bfr[j][0] = ds_rd128(Bb + j*16*128 + swz0);
                    bfr[j][1] = ds_rd128(Bb + j*16*128 + swz1);
                }
            }
#pragma unroll
            for (int ii = 0; ii < 2; ++ii) {
                const unsigned ra = Ab + (q*32 + ii*16)*128;
                af[ii][0] = ds_rd128(ra + swz0);
                af[ii][1] = ds_rd128(ra + swz1);
            }
            if (q == 0)      { if (t+1 < NT) stage(p^1, 0, 0, t+1); }
            else if (q == 1) { if (t+1 < NT) stage(p^1, 0, 1, t+1); }
            else if (q == 2) { if (t+2 < NT) stage(p, 1, 0, t+2); }
            else             { if (t+2 < NT) stage(p, 1, 1, t+2); }
            __builtin_amdgcn_s_barrier();
            asm volatile("s_waitcnt lgkmcnt(0)" ::: "memory");
            __builtin_amdgcn_sched_barrier(0);
            __builtin_amdgcn_s_setprio(1);
#pragma unroll
            for (int ii = 0; ii < 2; ++ii)
#pragma unroll
                for (int j = 0; j < 4; ++j)
#pragma unroll
                    for (int ks = 0; ks < 2; ++ks)
                        acc[q*2+ii][j] = __builtin_amdgcn_mfma_f32_16x16x32_bf16(
                            bfr[j][ks], af[ii][ks], acc[q*2+ii][j], 0, 0, 0);
            __builtin_amdgcn_s_setprio(0);
            if (q == 3) {
                if (t+2 < NT)      asm volatile("s_waitcnt vmcnt(4)" ::: "memory");
                else if (t+1 < NT) asm volatile("s_waitcnt vmcnt(0)" ::: "memory");
            }
            __builtin_amdgcn_s_barrier();
        }
    }

    // ---- epilogue via dead LDS, two 128-row halves, 1KB coalesced stores ----
    // write: row=i*16+lr (within half), cols wn4*64+j*16+quad*4+{0..3}; pad 264.
    // read/store: per instr 2 full rows (lane>>5 picks row, (lane&31)*16B cols).
#pragma unroll
    for (int hh = 0; hh < 2; ++hh) {
        __builtin_amdgcn_s_barrier();
        if (wm2 == hh) {
#pragma unroll
            for (int i = 0; i < 8; ++i) {
                const int row = i*16 + lr;
#pragma unroll
                for (int j = 0; j < 4; ++j) {
                    const int col = wn4*64 + j*16 + quad*4;
                    const f32x4 bv = *(const f32x4*)(bias + n0 + col);
                    u16x4 st;
#pragma unroll
                    for (int r = 0; r < 4; ++r)
                        st[r] = bf16r(acc[i][j][r] + bv[r]);
                    *(u16x4*)&lds[row*264 + col] = st;
                }
            }
        }
        __builtin_amdgcn_s_barrier();
#pragma unroll
        for (int k = 0; k < 8; ++k) {
            const int lrow = wave*16 + k*2 + (lane >> 5);
            const int grow = m0 + hh*128 + lrow;
            const int coff = (lane & 31) * 8;
            if (grow < M) {
                const u16x8 vv = *(const u16x8*)&lds[lrow*264 + coff];
                *(u16x8*)&C[(size_t)grow*ldc + n0 + coff] = vv;
            }
        }
    }
}

// ---------------- GEMM (NT) 128x128 (proj): C=A@W^T+bias ----------------
template<bool OUT_F32>
__global__ __launch_bounds__(256) void gemm_bt(
    const unsigned short* __restrict__ A, int lda,
    const unsigned short* __restrict__ W,
    const float* __restrict__ bias,
    void* __restrict__ Cptr, int ldc,
    int M, int Nd, int K)
{
    __shared__ alignas(16) unsigned short As[128*32];
    __shared__ alignas(16) unsigned short Bs[128*32];
    const int tid  = threadIdx.x;
    const int nwg = gridDim.x * gridDim.y;
    int orig = blockIdx.y * gridDim.x + blockIdx.x;
    const int q8 = nwg >> 3, r8 = nwg & 7;
    const int xcd = orig & 7, off = orig >> 3;
    const int wgid = (xcd < r8 ? xcd*(q8+1) : r8*(q8+1) + (xcd-r8)*q8) + off;
    const int n0   = (wgid % gridDim.x) * 128;
    const int m0   = (wgid / gridDim.x) * 128;
    const int lane = tid & 63;
    const int wave = tid >> 6;
    const int wm   = (wave >> 1) * 64;
    const int wn   = (wave & 1) * 64;
    const int lr   = lane & 15;
    const int quad = lane >> 4;

    const int r0 = tid >> 2, c0 = (tid & 3) * 8;
    const int r1 = r0 + 64;
    int am0 = m0 + r0; if (am0 > M-1) am0 = M-1;
    int am1 = m0 + r1; if (am1 > M-1) am1 = M-1;
    const unsigned short* a0 = A + (size_t)am0*lda + c0;
    const unsigned short* a1 = A + (size_t)am1*lda + c0;
    const unsigned short* w0 = W + (size_t)(n0+r0)*K + c0;
    const unsigned short* w1 = W + (size_t)(n0+r1)*K + c0;
    unsigned short* lA0 = As + tid*8;
    unsigned short* lA1 = As + (tid+256)*8;
    unsigned short* lB0 = Bs + tid*8;
    unsigned short* lB1 = Bs + (tid+256)*8;

    f32x4 acc[4][4] = {};
    for (int k0 = 0; k0 < K; k0 += 32) {
        __syncthreads();
        gl_lds16(a0 + k0, lA0);
        gl_lds16(a1 + k0, lA1);
        gl_lds16(w0 + k0, lB0);
        gl_lds16(w1 + k0, lB1);
        asm volatile("s_waitcnt vmcnt(0)" ::: "memory");
        __syncthreads();
        bf16x8 af[4], bfr[4];
#pragma unroll
        for (int i = 0; i < 4; ++i) {
            af[i]  = *(const bf16x8*)(As + (wm + i*16 + lr)*32 + quad*8);
            bfr[i] = *(const bf16x8*)(Bs + (wn + i*16 + lr)*32 + quad*8);
        }
#pragma unroll
        for (int i = 0; i < 4; ++i)
#pragma unroll
            for (int j = 0; j < 4; ++j)
                acc[i][j] = __builtin_amdgcn_mfma_f32_16x16x32_bf16(bfr[j], af[i], acc[i][j], 0, 0, 0);
    }
#pragma unroll
    for (int i = 0; i < 4; ++i) {
        const int row = m0 + wm + i*16 + lr;
        if (row < M) {
#pragma unroll
            for (int j = 0; j < 4; ++j) {
                const int col = n0 + wn + j*16 + quad*4;
                const f32x4 bv = *(const f32x4*)(bias + col);
                f32x4 v;
#pragma unroll
                for (int r = 0; r < 4; ++r) v[r] = acc[i][j][r] + bv[r];
                if (OUT_F32) {
                    *(f32x4*)&((float*)Cptr)[(size_t)row*ldc + col] = v;
                } else {
                    u16x4 st;
#pragma unroll
                    for (int r = 0; r < 4; ++r) st[r] = bf16r(v[r]);
                    *(u16x4*)&((__hip_bfloat16*)Cptr)[(size_t)row*ldc + col] = st;
                }
            }
        }
    }
}

// ---------------- kv partials via MFMA: kvp[chunk][bh][c][d] = sum_n ek[n,c]*v[n,d] ----
// 384 threads = 6 waves. Per 32-token subtile: stage ekT[96][32] (exp'd k, bf16)
// and vT[96][32] transposed into LDS (pad rows to 40 elems -> <=2-way banks).
// Wave w owns c-rows [w*16,w*16+16): A-frag = ekT rows, B-frag(fj) = vT rows
// fj*16+lr; 6 MFMAs/subtile accumulate over 8 subtiles. exp sums stay f32.
__global__ __launch_bounds__(384) void kv_mfma(
    const __hip_bfloat16* __restrict__ qkv,
    float* __restrict__ kvp,      // [NCHK][64][9216]
    float* __restrict__ spart)    // [NCHK][64][96]
{
    __shared__ alignas(16) unsigned short ekT[96*40];
    __shared__ alignas(16) unsigned short vT [96*40];
    __shared__ float sacc[384][8];
    const int bh = blockIdx.x, chunk = blockIdx.y;
    const int b = bh >> 3, h = bh & 7;
    const int nstart = chunk * CTOK;
    const int t = threadIdx.x;
    const int lane = t & 63, wave = t >> 6;
    const int lr = lane & 15, quad = lane >> 4;
    const int sr = t / 12, g = t % 12;      // staging: n-row (0..31), col-group
    const __hip_bfloat16* kb = qkv + (size_t)b*NN*2304 + 768 + h*96 + g*8;
    const __hip_bfloat16* vb = kb + 768;

    float ssum[8] = {0.f,0.f,0.f,0.f,0.f,0.f,0.f,0.f};
    f32x4 acc[6] = {};
#pragma unroll 1
    for (int s = 0; s < 8; ++s) {
        const int n = nstart + s*32 + sr;
        __syncthreads();                     // prior subtile's frag reads done
        {
            f32x8 ke = {0,0,0,0,0,0,0,0};
            u16x8 vraw = {0,0,0,0,0,0,0,0};
            if (n < NN) {
                const bf16x8 kr = *(const bf16x8*)(kb + (size_t)n*2304);
                vraw = *(const u16x8*)(vb + (size_t)n*2304);
                const f32x8 kf = __builtin_convertvector(kr, f32x8);
#pragma unroll
                for (int j = 0; j < 8; ++j) { ke[j] = __expf(kf[j]); ssum[j] += ke[j]; }
            }
#pragma unroll
            for (int e = 0; e < 8; ++e) {
                ekT[(g*8+e)*40 + sr] = bf16r(ke[e]);
                vT [(g*8+e)*40 + sr] = vraw[e];
            }
        }
        __syncthreads();
        const bf16x8 afr = *(const bf16x8*)(ekT + (wave*16 + lr)*40 + quad*8);
#pragma unroll
        for (int fj = 0; fj < 6; ++fj) {
            const bf16x8 bfrg = *(const bf16x8*)(vT + (fj*16 + lr)*40 + quad*8);
            acc[fj] = __builtin_amdgcn_mfma_f32_16x16x32_bf16(afr, bfrg, acc[fj], 0, 0, 0);
        }
    }
    // partial store: D row = c = wave*16+quad*4+r, col = d = fj*16+lr (m89)
    float* outp = kvp + (size_t)(chunk*64 + bh)*9216;
#pragma unroll
    for (int fj = 0; fj < 6; ++fj)
#pragma unroll
        for (int r = 0; r < 4; ++r)
            outp[(wave*16 + quad*4 + r)*96 + fj*16 + lr] = acc[fj][r];
    // column exp-sum reduce: col c fed by threads sr*12 + (c>>3), elem c&7
#pragma unroll
    for (int j = 0; j < 8; ++j) sacc[t][j] = ssum[j];
    __syncthreads();
    if (t < 96) {
        const int g2 = t >> 3, e2 = t & 7;
        float S = 0.f;
#pragma unroll
        for (int rr = 0; rr < 32; ++rr) S += sacc[rr*12 + g2][e2];
        spart[(size_t)(chunk*64 + bh)*96 + t] = S;
    }
}

// ---------------- kv reduce+normalize -> bf16 hi/lo transposed [d][c], stride 104 ----------------
__global__ __launch_bounds__(256) void kv_prep(
    const float* __restrict__ kvp, const float* __restrict__ spart,
    unsigned short* __restrict__ kvb)
{
    const int bh = blockIdx.x, y = blockIdx.y;
    __shared__ float sinv[24];
    const int t = threadIdx.x;
    const int cbase = y * 24;
    if (t < 24) {
        float S = 0.f;
#pragma unroll
        for (int ch = 0; ch < NCHK; ++ch)
            S += spart[(size_t)(ch*64 + bh)*96 + cbase + t];
        sinv[t] = 1.0f / S;
    }
    __syncthreads();
    unsigned short* dst = kvb + (size_t)bh*19968;
    for (int i = t; i < 2304; i += 256) {
        const int ii = y*2304 + i;
        const int c = ii / 96, d = ii % 96;
        float v = 0.f;
#pragma unroll
        for (int ch = 0; ch < NCHK; ++ch)
            v += kvp[(size_t)(ch*64 + bh)*9216 + ii];
        v *= sinv[c - cbase];
        const __hip_bfloat16 hb = __float2bfloat16(v);
        const float lo = v - __bfloat162float(hb);
        dst[d*104 + c]        = __hip_bfloat16_raw(hb).x;
        dst[9984 + d*104 + c] = bf16r(lo);
    }
}

// ---------------- att = scale*(q@kv) + pad(q_img*conv_v), MFMA version ----------------
__global__ __launch_bounds__(256) void fatt(
    const __hip_bfloat16* __restrict__ qkv,
    const unsigned short* __restrict__ kvb,
    const __hip_bfloat16* __restrict__ cv,
    __hip_bfloat16* __restrict__ att)
{
    __shared__ alignas(16) unsigned short kvs[2*96*104];
    const int tile = blockIdx.x, h = blockIdx.y, b = blockIdx.z;
    const int t = threadIdx.x, lane = t & 63, wave = t >> 6;
    const int lr = lane & 15, quad = lane >> 4;

    const unsigned short* kg = kvb + (size_t)(b*8 + h)*19968;
#pragma unroll
    for (int s = 0; s < 10; ++s) {
        const int slot = t + s*256;
        if (slot < 2496) gl_lds16(kg + slot*8, kvs + slot*8);
    }

    const int n0 = tile*128 + wave*32;
    const unsigned short* qbu = (const unsigned short*)qkv + (size_t)b*NN*2304 + h*96;
    bf16x8 af[2][3];
#pragma unroll
    for (int i = 0; i < 2; ++i) {
        int n = n0 + i*16 + lr; if (n > NN-1) n = NN-1;
#pragma unroll
        for (int kk = 0; kk < 3; ++kk)
            af[i][kk] = *(const bf16x8*)(qbu + (size_t)n*2304 + kk*32 + quad*8);
    }
    asm volatile("s_waitcnt vmcnt(0)" ::: "memory");
    __syncthreads();

    f32x4 acc[2][6] = {};
#pragma unroll
    for (int j = 0; j < 6; ++j) {
#pragma unroll
        for (int kk = 0; kk < 3; ++kk) {
            const bf16x8 bhh = *(const bf16x8*)(kvs + (j*16 + lr)*104 + kk*32 + quad*8);
            const bf16x8 bll = *(const bf16x8*)(kvs + 9984 + (j*16 + lr)*104 + kk*32 + quad*8);
#pragma unroll
            for (int i = 0; i < 2; ++i) {
                acc[i][j] = __builtin_amdgcn_mfma_f32_16x16x32_bf16(af[i][kk], bhh, acc[i][j], 0, 0, 0);
                acc[i][j] = __builtin_amdgcn_mfma_f32_16x16x32_bf16(af[i][kk], bll, acc[i][j], 0, 0, 0);
            }
        }
    }

    const float scale = 0.10206207261596577f;
    const __hip_bfloat16* qb  = (const __hip_bfloat16*)qbu;
    const __hip_bfloat16* cvb = cv + (size_t)(b*8 + h)*HW*96;
    __hip_bfloat16* ab = att + (size_t)b*NN*2304 + h*96;
#pragma unroll
    for (int i = 0; i < 2; ++i) {
#pragma unroll
        for (int j = 0; j < 6; ++j) {
            const int col = j*16 + lr;
#pragma unroll
            for (int r = 0; r < 4; ++r) {
                const int n = n0 + i*16 + quad*4 + r;
                if (n < NN) {
                    float v = scale * acc[i][j][r];
                    if (n > 0) {
                        const float qv = __bfloat162float(qb[(size_t)n*2304 + col]);
                        v += qv * __bfloat162float(cvb[(size_t)(n-1)*96 + col]);
                    }
                    ab[(size_t)n*2304 + col] = __float2bfloat16(v);
                }
            }
        }
    }
}

// ---------------- depthwise conv v2: LDS row-band ring, 32-ch groups ----------------
template<int KS>
__device__ __forceinline__ void dw_band(
    float (*vt)[64][36],
    const __hip_bfloat16* __restrict__ vbase,
    const float* __restrict__ wp, float bv,
    __hip_bfloat16* __restrict__ cvo,
    int y0)
{
    constexpr int P = KS/2;
    const int t = threadIdx.x;
    float wr[KS*KS];
#pragma unroll
    for (int i = 0; i < KS*KS; ++i) wr[i] = wp[i];

    const int spx = t >> 2, sc0 = (t & 3) * 8;
    const int ch = t & 31, xs = t >> 5;
    const int xbase = xs*7 + 4 - P;

#pragma unroll
    for (int r = -P; r < P; ++r) {
        const int y = y0 + r;
        if (t < 224) {
            f32x8 v8 = {0,0,0,0,0,0,0,0};
            if ((unsigned)y < (unsigned)IMG) {
                const bf16x8 rv = *(const bf16x8*)(vbase + (size_t)(y*IMG + spx)*2304 + sc0);
                v8 = __builtin_convertvector(rv, f32x8);
            }
            float* dst = &vt[(y+8)&7][spx+4][sc0];
            *(f32x4*)dst     = *(f32x4*)&v8;
            *(f32x4*)(dst+4) = *((f32x4*)&v8 + 1);
        }
    }

    for (int yy = y0; yy < y0 + 14; ++yy) {
        {
            const int y = yy + P;
            if (t < 224) {
                f32x8 v8 = {0,0,0,0,0,0,0,0};
                if ((unsigned)y < (unsigned)IMG) {
                    const bf16x8 rv = *(const bf16x8*)(vbase + (size_t)(y*IMG + spx)*2304 + sc0);
                    v8 = __builtin_convertvector(rv, f32x8);
                }
                float* dst = &vt[(y+8)&7][spx+4][sc0];
                *(f32x4*)dst     = *(f32x4*)&v8;
                *(f32x4*)(dst+4) = *((f32x4*)&v8 + 1);
            }
        }
        __syncthreads();
        float acc[7];
#pragma unroll
        for (int j = 0; j < 7; ++j) acc[j] = bv;
        for (int dy = 0; dy < KS; ++dy) {
            const float* rowp = &vt[(yy + dy - P + 8) & 7][0][ch] + xbase*36;
            float win[7 + 2*P];
#pragma unroll
            for (int i = 0; i < 7 + 2*P; ++i) win[i] = rowp[i*36];
#pragma unroll
            for (int dx = 0; dx < KS; ++dx)
#pragma unroll
                for (int j = 0; j < 7; ++j)
                    acc[j] += wr[dy*KS+dx] * win[j+dx];
        }
        const int p0 = yy*IMG + xs*7;
#pragma unroll
        for (int j = 0; j < 7; ++j)
            cvo[(size_t)(p0 + j)*96] = __float2bfloat16(acc[j]);
        __syncthreads();
    }
}

__global__ __launch_bounds__(256) void dwconv2(
    const __hip_bfloat16* __restrict__ qkv,
    const float* __restrict__ w3, const float* __restrict__ b3,
    const float* __restrict__ w5, const float* __restrict__ b5,
    const float* __restrict__ w7, const float* __restrict__ b7,
    __hip_bfloat16* __restrict__ cv)
{
    __shared__ float vt[8][64][36];
    const int band = blockIdx.x, grp = blockIdx.y, b = blockIdx.z;
    const int t = threadIdx.x;
    {
        const int s = t >> 5, i = t & 31;
        const int xi = i >> 2;
        const int xp = (xi < 4) ? xi : 56 + xi;
        const int c0 = (i & 3) * 8;
        const f32x4 z = {0.f, 0.f, 0.f, 0.f};
        *(f32x4*)&vt[s][xp][c0]     = z;
        *(f32x4*)&vt[s][xp][c0+4]   = z;
    }
    const int chbase = grp * 32;
    const int wg = chbase + (t & 31);
    const int h = wg / 96, d = wg % 96;
    const int y0 = band * 14;
    const __hip_bfloat16* vbase = qkv + (size_t)b*NN*2304 + 2304 + 1536 + chbase;
    __hip_bfloat16* cvo = cv + ((size_t)(b*8 + h)*HW)*96 + d;
    if (grp < 6)        dw_band<3>(vt, vbase, w3 + wg*9,        b3[wg],     cvo, y0);
    else if (grp < 15)  dw_band<5>(vt, vbase, w5 + (wg-192)*25, b5[wg-192], cvo, y0);
    else                dw_band<7>(vt, vbase, w7 + (wg-480)*49, b7[wg-480], cvo, y0);
}

extern "C" void kernel_launch(void* const* d_in, const int* in_sizes, int n_in,
                              void* d_out, int out_size, void* d_ws, size_t ws_size,
                              hipStream_t stream)
{
    const float* x      = (const float*)d_in[0];
    const float* qkv_w  = (const float*)d_in[1];
    const float* qkv_b  = (const float*)d_in[2];
    const float* proj_w = (const float*)d_in[3];
    const float* proj_b = (const float*)d_in[4];
    const float* w3 = (const float*)d_in[5];
    const float* b3 = (const float*)d_in[6];
    const float* w5 = (const float*)d_in[7];
    const float* b5 = (const float*)d_in[8];
    const float* w7 = (const float*)d_in[9];
    const float* b7 = (const float*)d_in[10];
    float* out = (float*)d_out;

    char* ws = (char*)d_ws;
    const size_t QKV_B = (size_t)MTOK * 2304 * 2;       // 115,642,368
    const size_t XB_B  = (size_t)MTOK * 768 * 2;        //  38,547,456
    const size_t SH_B  = XB_B;                           //  >= kvp+spart (30.9MB) and cv
    const size_t KV_B  = (size_t)64 * 9216 * 4;
    const size_t ST_B  = 49152;
    const size_t WB_B  = (size_t)2304 * 768 * 2;
    const size_t PW_B  = (size_t)768 * 768 * 2;
    if (ws_size < QKV_B + SH_B + KV_B + ST_B + WB_B + PW_B) return;
    __hip_bfloat16* qkv  = (__hip_bfloat16*)ws;
    unsigned short* xb   = (unsigned short*)(ws + QKV_B);
    float*          kvp  = (float*)(ws + QKV_B);
    float*          spart= (float*)(ws + QKV_B + (size_t)NCHK*64*9216*4);
    __hip_bfloat16* cv   = (__hip_bfloat16*)(ws + QKV_B);
    unsigned short* wb   = (unsigned short*)(ws + QKV_B + SH_B + KV_B + ST_B);
    unsigned short* pwb  = (unsigned short*)(ws + QKV_B + SH_B + KV_B + ST_B + WB_B);

    // 0) convert x and weights to bf16 (one-time)
    cvt_bf16<<<(MTOK*768/8 + 255)/256, 256, 0, stream>>>(x, xb, MTOK*768/8);
    cvt_bf16<<<(2304*768/8 + 255)/256, 256, 0, stream>>>(qkv_w, wb, 2304*768/8);
    cvt_bf16<<<(768*768/8 + 255)/256, 256, 0, stream>>>(proj_w, pwb, 768*768/8);
    // 1) qkv = x @ qkv_w^T + b  (256^2 8-phase)  -> [25096, 2304] bf16
    gemm256<<<dim3(9, 99), 512, 0, stream>>>(
        xb, wb, qkv_b, (unsigned short*)qkv, 768, 768, 2304, MTOK, 768/64);
    // 2) kv partials via MFMA (unnormalized exp) + per-column exp-sums
    kv_mfma<<<dim3(64, NCHK), 384, 0, stream>>>(qkv, kvp, spart);
    // 3) reduce partials, normalize, hi/lo transpose -> kvb (dead qkv_wb region)
    kv_prep<<<dim3(64, 4), 256, 0, stream>>>(kvp, spart, wb);
    // 4) depthwise conv on v image -> cv (overwrites dead kvp)
    dwconv2<<<dim3(4, 24, 8), 256, 0, stream>>>(qkv, w3, b3, w5, b5, w7, b7, cv);
    // 5) att = scale * q@kv + crpe  -> dead k-section of qkv buffer (MFMA)
    fatt<<<dim3(25, 8, 8), 256, 0, stream>>>(qkv, wb, cv,
                                             (__hip_bfloat16*)ws + 768);
    // 6) out = att @ proj_w^T + proj_b  -> f32 d_out
    gemm_bt<true><<<dim3(6, 197), 256, 0, stream>>>(
        (const unsigned short*)ws + 768, 2304, pwb, proj_b, out, 768,
        MTOK, 768, 768);
}